// Round 20
// baseline (540.094 us; speedup 1.0000x reference)
//
#include <hip/hip_runtime.h>
#include <math.h>

#define N_ATOMS 60000
#define M_NBR   12
#define D_FEA   64
#define NBR_FEA 41
#define B_CRY   1200
#define NA_CRY  50
#define EPSV    1e-5f

#define NBLK_MAIN 2048   // blocks for k_stats (4 waves each)

__device__ __forceinline__ float wsum(float v){
#pragma unroll
  for (int o = 32; o > 0; o >>= 1) v += __shfl_xor(v, o, 64);
  return v;
}
__device__ __forceinline__ float wmax64(float v){
#pragma unroll
  for (int o = 32; o > 0; o >>= 1) v = fmaxf(v, __shfl_xor(v, o, 64));
  return v;
}
__device__ __forceinline__ float softplusf(float x){
  return fmaxf(x, 0.f) + __logf(1.f + __expf(-fabsf(x)));
}
__device__ __forceinline__ float sigmoidf(float x){
  return 1.f / (1.f + __expf(-x));
}
// round-to-nearest-even fp32 -> bf16 bits (low 16)
__device__ __forceinline__ unsigned bf16_rne(float x){
  unsigned u = __float_as_uint(x);
  return (u + 0x7fffu + ((u >> 16) & 1u)) >> 16;
}
__device__ __forceinline__ unsigned pack2(float lo, float hi){
  return bf16_rne(lo) | (bf16_rne(hi) << 16);
}
__device__ __forceinline__ float unlo(unsigned u){ return __uint_as_float(u << 16); }
__device__ __forceinline__ float unhi(unsigned u){ return __uint_as_float(u & 0xffff0000u); }

// ---------------- K1: transformer + fused projections -----------------------
// r19 structure (166us) with phase 7+8 FUSED: t is already register-resident
// per row in phase 7 (lane=channel); LN2's wsum runs immediately -> one less
// barrier and no s_b round-trip for t. Row-local: phases 7/8 touch only the
// wave's own rows; the phase-6 barrier orders h1 production.
__global__ __launch_bounds__(512, 4) void k_transformer(
    const float* __restrict__ atom_in, const float* __restrict__ adj,
    const float* __restrict__ w1, const float* __restrict__ b1,
    const float* __restrict__ w2, const float* __restrict__ b2,
    const float* __restrict__ g1v, const float* __restrict__ be1,
    const float* __restrict__ g2v, const float* __restrict__ be2,
    const int* __restrict__ cidx, const float* __restrict__ fc_w,
    const float* __restrict__ fc_b, float* __restrict__ atom_tf,
    unsigned* __restrict__ proj1p, unsigned* __restrict__ proj2p)
{
  __shared__ float s_a[NA_CRY * D_FEA];        // src / LN1 / LN2-out
  __shared__ float s_b[D_FEA * (NA_CRY + 1)];  // srcT(stride 51) / x
  __shared__ float s_c[NA_CRY * D_FEA];        // scores / h1 / atom_in rows
  __shared__ int   s_gi[NA_CRY];               // gathered atom ids

  const int tid  = threadIdx.x;
  const int b    = blockIdx.x;
  const int lane = tid & 63;
  const int w    = tid >> 6;   // 0..7

  // phase 1: load src (gather) + transposed copy (stride 51); stash ids
  if (tid < NA_CRY) s_gi[tid] = cidx[b * NA_CRY + tid];
  for (int p = tid; p < NA_CRY * D_FEA; p += 512){
    int i = p >> 6, d = p & 63;
    int a = cidx[b * NA_CRY + i];
    float v = atom_in[a * D_FEA + d];
    s_a[p] = v;
    s_b[d * (NA_CRY + 1) + i] = v;
  }
  __syncthreads();

  // phase 2: scores = (src . src^T) * scale * adj, 2x2 tile per thread
  const float scale = 0.125f; // 1/sqrt(64)
  {
    const float* adjb = adj + (size_t)b * NA_CRY * NA_CRY;
    for (int t = tid; t < 625; t += 512){
      int i0 = (t / 25) * 2, j0 = (t % 25) * 2;
      float a00 = 0.f, a01 = 0.f, a10 = 0.f, a11 = 0.f;
#pragma unroll 8
      for (int d = 0; d < D_FEA; ++d){
        float va0 = s_a[i0 * D_FEA + d];
        float va1 = s_a[(i0 + 1) * D_FEA + d];
        float vb0 = s_b[d * (NA_CRY + 1) + j0];
        float vb1 = s_b[d * (NA_CRY + 1) + j0 + 1];
        a00 += va0 * vb0; a01 += va0 * vb1;
        a10 += va1 * vb0; a11 += va1 * vb1;
      }
      s_c[i0 * NA_CRY + j0]           = a00 * scale * adjb[i0 * NA_CRY + j0];
      s_c[i0 * NA_CRY + j0 + 1]       = a01 * scale * adjb[i0 * NA_CRY + j0 + 1];
      s_c[(i0 + 1) * NA_CRY + j0]     = a10 * scale * adjb[(i0 + 1) * NA_CRY + j0];
      s_c[(i0 + 1) * NA_CRY + j0 + 1] = a11 * scale * adjb[(i0 + 1) * NA_CRY + j0 + 1];
    }
  }
  __syncthreads();

  // phase 3: softmax over rows (wave per row)
  for (int r = w; r < NA_CRY; r += 8){
    float v = (lane < NA_CRY) ? s_c[r * NA_CRY + lane] : -1e30f;
    float mx = wmax64(v);
    float e = (lane < NA_CRY) ? __expf(v - mx) : 0.f;
    float s = wsum(e);
    if (lane < NA_CRY) s_c[r * NA_CRY + lane] = e / s;
  }
  __syncthreads();

  // phase 4: x = src + attn @ src -> s_b; 2 rows/thread share s_a[m][d].
  for (int t = tid; t < 25 * D_FEA; t += 512){
    int nh = t >> 6, d = t & 63;
    int n0 = nh * 2, n1 = n0 + 1;
    float x0 = 0.f, x1 = 0.f;
#pragma unroll 10
    for (int m = 0; m < NA_CRY; ++m){
      float sa = s_a[m * D_FEA + d];
      x0 += s_c[n0 * NA_CRY + m] * sa;
      x1 += s_c[n1 * NA_CRY + m] * sa;
    }
    s_b[n0 * D_FEA + d] = s_a[n0 * D_FEA + d] + x0;
    s_b[n1 * D_FEA + d] = s_a[n1 * D_FEA + d] + x1;
  }
  __syncthreads();

  // phase 5: LN1 -> s_a
  for (int r = w; r < NA_CRY; r += 8){
    float x = s_b[r * D_FEA + lane];
    float mu = wsum(x) * (1.f / 64.f);
    float dx = x - mu;
    float var = wsum(dx * dx) * (1.f / 64.f);
    s_a[r * D_FEA + lane] = dx * rsqrtf(var + EPSV) * g1v[lane] + be1[lane];
  }
  __syncthreads();

  // phase 6: h1 = relu(LN1 @ w1 + b1) -> s_c  (2 rows x 2 k-parities)
  for (int n0 = w * 2; n0 < NA_CRY; n0 += 16){
    const int n1 = n0 + 1;
    float x00 = 0.f, x01 = 0.f, x10 = 0.f, x11 = 0.f;
#pragma unroll
    for (int k = 0; k < D_FEA; k += 2){
      float wv0 = w1[k * D_FEA + lane];
      float wv1 = w1[(k + 1) * D_FEA + lane];
      x00 += s_a[n0 * D_FEA + k] * wv0;
      x01 += s_a[n0 * D_FEA + k + 1] * wv1;
      x10 += s_a[n1 * D_FEA + k] * wv0;
      x11 += s_a[n1 * D_FEA + k + 1] * wv1;
    }
    float bb = b1[lane];
    s_c[n0 * D_FEA + lane] = fmaxf(bb + x00 + x01, 0.f);
    s_c[n1 * D_FEA + lane] = fmaxf(bb + x10 + x11, 0.f);
  }
  __syncthreads();

  // phase 7+8 fused: t = LN1 + h1 @ w2 + b2, then LN2 in-register ->
  // atom_tf + s_a (own rows only; no barrier, no s_b traffic)
  for (int n0 = w * 2; n0 < NA_CRY; n0 += 16){
    const int n1 = n0 + 1;
    float x00 = 0.f, x01 = 0.f, x10 = 0.f, x11 = 0.f;
#pragma unroll
    for (int k = 0; k < D_FEA; k += 2){
      float wv0 = w2[k * D_FEA + lane];
      float wv1 = w2[(k + 1) * D_FEA + lane];
      x00 += s_c[n0 * D_FEA + k] * wv0;
      x01 += s_c[n0 * D_FEA + k + 1] * wv1;
      x10 += s_c[n1 * D_FEA + k] * wv0;
      x11 += s_c[n1 * D_FEA + k + 1] * wv1;
    }
    float bb = b2[lane];
    float t0 = s_a[n0 * D_FEA + lane] + bb + x00 + x01;
    float t1 = s_a[n1 * D_FEA + lane] + bb + x10 + x11;
    // LN2 row n0
    {
      float mu = wsum(t0) * (1.f / 64.f);
      float dx = t0 - mu;
      float var = wsum(dx * dx) * (1.f / 64.f);
      float res = dx * rsqrtf(var + EPSV) * g2v[lane] + be2[lane];
      atom_tf[(size_t)(b * NA_CRY + n0) * D_FEA + lane] = res;
      s_a[n0 * D_FEA + lane] = res;
    }
    // LN2 row n1
    {
      float mu = wsum(t1) * (1.f / 64.f);
      float dx = t1 - mu;
      float var = wsum(dx * dx) * (1.f / 64.f);
      float res = dx * rsqrtf(var + EPSV) * g2v[lane] + be2[lane];
      atom_tf[(size_t)(b * NA_CRY + n1) * D_FEA + lane] = res;
      s_a[n1 * D_FEA + lane] = res;
    }
  }
  __syncthreads();

  // phase 9a: re-gather atom_in rows into s_c (h1 dead)
  for (int p = tid; p < NA_CRY * D_FEA; p += 512){
    int i = p >> 6, d = p & 63;
    s_c[p] = atom_in[(size_t)s_gi[i] * D_FEA + d];
  }
  __syncthreads();

  // phase 9b: fused projections, 4 rows share each fc_w load quartet.
  for (int n0 = w * 4; n0 < NA_CRY; n0 += 32){
    const int nb = (n0 + 1 < NA_CRY) ? n0 + 1 : NA_CRY - 1;
    const int nc = (n0 + 2 < NA_CRY) ? n0 + 2 : NA_CRY - 1;
    const int nd = (n0 + 3 < NA_CRY) ? n0 + 3 : NA_CRY - 1;
    const int c = lane;
    const float bb0 = fc_b[c], bb1 = fc_b[64 + c];
    float A1 = bb0, A2 = bb1, A3 = 0.f, A4 = 0.f;
    float B1 = bb0, B2 = bb1, B3 = 0.f, B4 = 0.f;
    float C1 = bb0, C2 = bb1, C3 = 0.f, C4 = 0.f;
    float D1 = bb0, D2 = bb1, D3 = 0.f, D4 = 0.f;
#pragma unroll 4
    for (int k = 0; k < D_FEA; ++k){
      float w0 = fc_w[k * 128 + c];
      float w6 = fc_w[k * 128 + 64 + c];
      float v0 = fc_w[(64 + k) * 128 + c];
      float v6 = fc_w[(64 + k) * 128 + 64 + c];
      float ta = s_a[n0 * 64 + k], tb = s_a[nb * 64 + k];
      float tc = s_a[nc * 64 + k], td = s_a[nd * 64 + k];
      float sa = s_c[n0 * 64 + k], sb = s_c[nb * 64 + k];
      float sc = s_c[nc * 64 + k], sd = s_c[nd * 64 + k];
      A1 += ta * w0; A2 += ta * w6; A3 += sa * v0; A4 += sa * v6;
      B1 += tb * w0; B2 += tb * w6; B3 += sb * v0; B4 += sb * v6;
      C1 += tc * w0; C2 += tc * w6; C3 += sc * v0; C4 += sc * v6;
      D1 += td * w0; D2 += td * w6; D3 += sd * v0; D4 += sd * v6;
    }
    proj1p[(size_t)(b * NA_CRY + n0) * 64 + c] = pack2(A1, A2);
    proj2p[(size_t)s_gi[n0] * 64 + c] = pack2(A3, A4);
    if (n0 + 1 < NA_CRY){
      proj1p[(size_t)(b * NA_CRY + nb) * 64 + c] = pack2(B1, B2);
      proj2p[(size_t)s_gi[nb] * 64 + c] = pack2(B3, B4);
    }
    if (n0 + 2 < NA_CRY){
      proj1p[(size_t)(b * NA_CRY + nc) * 64 + c] = pack2(C1, C2);
      proj2p[(size_t)s_gi[nc] * 64 + c] = pack2(C3, C4);
    }
    if (n0 + 3 < NA_CRY){
      proj1p[(size_t)(b * NA_CRY + nd) * 64 + c] = pack2(D1, D2);
      proj2p[(size_t)s_gi[nd] * 64 + c] = pack2(D3, D4);
    }
  }
}

// ---------------- K3: BN1 stats + store pre-BN g (bf16x2) -------------------
// r16-proven structure; r19 upgrade: 16B global_load_lds staging (2 ops/atom
// instead of 8: op1 lanes 0-63 cover floats 0-255; op2 lanes 0-58 cover
// floats 256-491 exactly). 1968B atom stride keeps 16B alignment. vmcnt(2)
// keeps the 2 stage ops in flight while draining rw/p1v.
#define LOADRW(MM) unsigned rw##MM = proj2p[(size_t)__builtin_amdgcn_readfirstlane(jrow[MM]) * 64 + lane];

#define STAGE(AA, BUF) { \
    const float* srcp = nbr_fea + (size_t)(AA) * (M_NBR * NBR_FEA); \
    float* dstp = s_frow + (w * 2 + (BUF)) * 512; \
    __builtin_amdgcn_global_load_lds(srcp + lane * 4, dstp, 16, 0, 0); \
    if (lane < 59) \
      __builtin_amdgcn_global_load_lds(srcp + 256 + lane * 4, dstp + 256, 16, 0, 0); \
  }

#define GBODY(MM) { \
    float g0 = p10 + unlo(rw##MM); \
    float g1 = p11 + unhi(rw##MM); \
    _Pragma("unroll") \
    for (int k = 0; k < NBR_FEA; ++k){ \
      float aa = fr[MM * NBR_FEA + k]; \
      g0 += aa * unlo(wbp[k]); \
      g1 += aa * unhi(wbp[k]); \
    } \
    if (STORE) gated[(size_t)(base + MM) * 64 + lane] = pack2(g0, g1); \
    s0 += g0; q0 += g0 * g0; \
    s1 += g1; q1 += g1 * g1; }

template<int STORE>
__global__ __launch_bounds__(256) void k_stats(
    const float* __restrict__ nbr_fea, const int* __restrict__ nbr_idx,
    const float* __restrict__ fc_w, const unsigned* __restrict__ proj1p,
    const unsigned* __restrict__ proj2p, float* __restrict__ part1,
    unsigned* __restrict__ gated)
{
  __shared__ float red[1024];
  __shared__ float s_frow[4 * 2 * 512];  // 4 waves x double-buffer x 512 floats
  const int tid = threadIdx.x, lane = tid & 63, w = tid >> 6;

  unsigned wbp[NBR_FEA];
#pragma unroll
  for (int k = 0; k < NBR_FEA; ++k){
    float w0 = fc_w[(128 + k) * 128 + lane];
    float w1 = fc_w[(128 + k) * 128 + 64 + lane];
    wbp[k] = pack2(w0, w1);
  }

  const int gw = blockIdx.x * 4 + w, nw = gridDim.x * 4;
  const int q = N_ATOMS / nw, rr = N_ATOMS % nw;
  const int a0 = gw * q + (gw < rr ? gw : rr);
  const int a1 = a0 + q + (gw < rr ? 1 : 0);
  float s0 = 0.f, s1 = 0.f, q0 = 0.f, q1 = 0.f;
  int cur = 0;
  if (a0 < a1){ STAGE(a0, 0); }
  for (int a = a0; a < a1; ++a){
    const int au = __builtin_amdgcn_readfirstlane(a);
    const int base = au * M_NBR;
    const int* jrow = nbr_idx + base;            // uniform -> s_load (tiny)
    unsigned p1v = proj1p[(size_t)au * 64 + lane];
    LOADRW(0) LOADRW(1) LOADRW(2) LOADRW(3) LOADRW(4) LOADRW(5)
    LOADRW(6) LOADRW(7) LOADRW(8) LOADRW(9) LOADRW(10) LOADRW(11)
    const int anext = (a + 1 < a1) ? (a + 1) : a;
    STAGE(anext, cur ^ 1);                       // 2 newest vmem ops
    asm volatile("s_waitcnt vmcnt(2)" ::: "memory");  // drain rw/p1 + prior stage
    const float* fr = s_frow + (w * 2 + cur) * 512;
    const float p10 = unlo(p1v), p11 = unhi(p1v);
    GBODY(0) GBODY(1) GBODY(2) GBODY(3) GBODY(4) GBODY(5)
    GBODY(6) GBODY(7) GBODY(8) GBODY(9) GBODY(10) GBODY(11)
    cur ^= 1;
  }
  red[w * 256 + lane]        = s0;
  red[w * 256 + 64 + lane]   = s1;
  red[w * 256 + 128 + lane]  = q0;
  red[w * 256 + 192 + lane]  = q1;
  __syncthreads();
  float v = red[tid] + red[256 + tid] + red[512 + tid] + red[768 + tid];
  part1[blockIdx.x * 256 + tid] = v;   // [0:128]=sum(ch), [128:256]=sumsq(ch)
}

// finish BN1 stats: stats1[c]=scale, stats1[128+c]=shift
__global__ __launch_bounds__(1024) void k_stats_fin(
    const float* __restrict__ part1, const float* __restrict__ bn1_g,
    const float* __restrict__ bn1_b, float* __restrict__ stats1)
{
  __shared__ float red2[4 * 256];
  __shared__ float col[256];
  const int tid = threadIdx.x;
  const int c = tid & 255, g = tid >> 8;  // 4 groups
  float v = 0.f;
  for (int b = g; b < NBLK_MAIN; b += 4) v += part1[b * 256 + c];
  red2[g * 256 + c] = v;
  __syncthreads();
  if (g == 0) col[c] = red2[c] + red2[256 + c] + red2[512 + c] + red2[768 + c];
  __syncthreads();
  if (tid < 128){
    const float inv = 1.f / (float)(N_ATOMS * M_NBR);
    float mu = col[tid] * inv;
    float var = col[128 + tid] * inv - mu * mu;
    float sc = bn1_g[tid] * rsqrtf(var + EPSV);
    stats1[tid] = sc;
    stats1[128 + tid] = bn1_b[tid] - mu * sc;
  }
}

// ---------------- K4a (gated path): streaming BN1+gate+sum ------------------
__global__ __launch_bounds__(256) void k_reduce_g(
    const unsigned* __restrict__ gated, const float* __restrict__ stats1,
    float* __restrict__ nbr_sumed, float* __restrict__ part2)
{
  __shared__ float red[512];
  const int tid = threadIdx.x, lane = tid & 63, w = tid >> 6;
  const float sc0 = stats1[lane],       sc1 = stats1[64 + lane];
  const float tc0 = stats1[128 + lane], tc1 = stats1[192 + lane];
  const int wg = blockIdx.x * 4 + w, nw = gridDim.x * 4;
  float bs = 0.f, bq = 0.f;
  for (int a = wg; a < N_ATOMS; a += nw){
    const size_t base = (size_t)a * M_NBR * 64 + lane;
    float acc = 0.f;
#pragma unroll
    for (int m = 0; m < M_NBR; ++m){
      unsigned gv = gated[base + m * 64];
      acc += sigmoidf(unlo(gv) * sc0 + tc0) * softplusf(unhi(gv) * sc1 + tc1);
    }
    nbr_sumed[(size_t)a * 64 + lane] = acc;
    bs += acc; bq += acc * acc;
  }
  red[w * 128 + lane]      = bs;
  red[w * 128 + 64 + lane] = bq;
  __syncthreads();
  if (tid < 128){
    float v = red[tid] + red[128 + tid] + red[256 + tid] + red[384 + tid];
    part2[blockIdx.x * 128 + tid] = v;  // [0:64]=sum, [64:128]=sumsq
  }
}

// ---------------- K4b (fallback): recompute g, BN1, gate, sum ---------------
#define GBODYR(MM) { \
    const float* frow = nbr_fea + (size_t)(base + MM) * NBR_FEA; \
    float g0 = p10 + unlo(rw##MM); \
    float g1 = p11 + unhi(rw##MM); \
    _Pragma("unroll") \
    for (int k = 0; k < NBR_FEA; ++k){ \
      float aa = frow[k]; \
      g0 += aa * unlo(wbp[k]); \
      g1 += aa * unhi(wbp[k]); \
    } \
    acc += sigmoidf(g0 * sc0 + tc0) * softplusf(g1 * sc1 + tc1); }

__global__ __launch_bounds__(256) void k_reduce_r(
    const float* __restrict__ nbr_fea, const int* __restrict__ nbr_idx,
    const float* __restrict__ fc_w, const unsigned* __restrict__ proj1p,
    const unsigned* __restrict__ proj2p, const float* __restrict__ stats1,
    float* __restrict__ nbr_sumed, float* __restrict__ part2)
{
  __shared__ float red[512];
  const int tid = threadIdx.x, lane = tid & 63, w = tid >> 6;
  unsigned wbp[NBR_FEA];
#pragma unroll
  for (int k = 0; k < NBR_FEA; ++k){
    float w0 = fc_w[(128 + k) * 128 + lane];
    float w1 = fc_w[(128 + k) * 128 + 64 + lane];
    wbp[k] = pack2(w0, w1);
  }
  const float sc0 = stats1[lane],       sc1 = stats1[64 + lane];
  const float tc0 = stats1[128 + lane], tc1 = stats1[192 + lane];
  const int gw = blockIdx.x * 4 + w, nw = gridDim.x * 4;
  const int q = N_ATOMS / nw, rr = N_ATOMS % nw;
  const int a0 = gw * q + (gw < rr ? gw : rr);
  const int a1 = a0 + q + (gw < rr ? 1 : 0);
  float bs = 0.f, bq = 0.f;
  for (int a = a0; a < a1; ++a){
    const int au = __builtin_amdgcn_readfirstlane(a);
    const int base = au * M_NBR;
    const int* jrow = nbr_idx + base;
    unsigned p1v = proj1p[(size_t)au * 64 + lane];
    LOADRW(0) LOADRW(1) LOADRW(2) LOADRW(3) LOADRW(4) LOADRW(5)
    LOADRW(6) LOADRW(7) LOADRW(8) LOADRW(9) LOADRW(10) LOADRW(11)
    const float p10 = unlo(p1v), p11 = unhi(p1v);
    float acc = 0.f;
    GBODYR(0) GBODYR(1) GBODYR(2) GBODYR(3) GBODYR(4) GBODYR(5)
    GBODYR(6) GBODYR(7) GBODYR(8) GBODYR(9) GBODYR(10) GBODYR(11)
    nbr_sumed[(size_t)au * 64 + lane] = acc;
    bs += acc; bq += acc * acc;
  }
  red[w * 128 + lane]      = bs;
  red[w * 128 + 64 + lane] = bq;
  __syncthreads();
  if (tid < 128){
    float v = red[tid] + red[128 + tid] + red[256 + tid] + red[384 + tid];
    part2[blockIdx.x * 128 + tid] = v;
  }
}

// finish BN2 stats
__global__ __launch_bounds__(1024) void k_red_fin(
    const float* __restrict__ part2, const float* __restrict__ bn2_g,
    const float* __restrict__ bn2_b, float* __restrict__ stats2)
{
  __shared__ float red2[8 * 128];
  __shared__ float col[128];
  const int tid = threadIdx.x;
  const int c = tid & 127, g = tid >> 7;  // 8 groups
  float v = 0.f;
  for (int b = g; b < NBLK_MAIN; b += 8) v += part2[b * 128 + c];
  red2[g * 128 + c] = v;
  __syncthreads();
  if (g == 0){
    float t = 0.f;
#pragma unroll
    for (int gg = 0; gg < 8; ++gg) t += red2[gg * 128 + c];
    col[c] = t;
  }
  __syncthreads();
  if (tid < 64){
    const float inv = 1.f / (float)N_ATOMS;
    float mu = col[tid] * inv;
    float var = col[64 + tid] * inv - mu * mu;
    float sc = bn2_g[tid] * rsqrtf(var + EPSV);
    stats2[tid] = sc;
    stats2[64 + tid] = bn2_b[tid] - mu * sc;
  }
}

// ---------------- K5: out = softplus(atom_tf + BN2(nbr_sumed)) --------------
__global__ __launch_bounds__(256) void k_final(
    const float* __restrict__ atom_tf, const float* __restrict__ ns,
    const float* __restrict__ stats2, float* __restrict__ out)
{
  int i = blockIdx.x * 256 + threadIdx.x;
  if (i >= N_ATOMS * 64) return;
  int c = i & 63;
  float x = atom_tf[i] + ns[i] * stats2[c] + stats2[64 + c];
  out[i] = softplusf(x);
}

extern "C" void kernel_launch(void* const* d_in, const int* in_sizes, int n_in,
                              void* d_out, int out_size, void* d_ws, size_t ws_size,
                              hipStream_t stream)
{
  const float* atom_in = (const float*)d_in[0];
  const float* nbr_fea = (const float*)d_in[1];
  const float* adj     = (const float*)d_in[2];
  const float* w1 = (const float*)d_in[3];
  const float* b1 = (const float*)d_in[4];
  const float* w2 = (const float*)d_in[5];
  const float* b2 = (const float*)d_in[6];
  const float* tln1_g = (const float*)d_in[7];
  const float* tln1_b = (const float*)d_in[8];
  const float* tln2_g = (const float*)d_in[9];
  const float* tln2_b = (const float*)d_in[10];
  const float* fc_w = (const float*)d_in[11];
  const float* fc_b = (const float*)d_in[12];
  const float* bn1_g = (const float*)d_in[13];
  const float* bn1_b = (const float*)d_in[14];
  const float* bn2_g = (const float*)d_in[15];
  const float* bn2_b = (const float*)d_in[16];
  const int* nbr_idx = (const int*)d_in[17];
  const int* cidx    = (const int*)d_in[18];
  float* out = (float*)d_out;

  char* ws = (char*)d_ws;
  size_t off = 0;
  float* atom_tf = (float*)(ws + off);    off += (size_t)N_ATOMS * 64 * 4;
  unsigned* proj1p = (unsigned*)(ws + off); off += (size_t)N_ATOMS * 64 * 4;
  unsigned* proj2p = (unsigned*)(ws + off); off += (size_t)N_ATOMS * 64 * 4;
  float* nbr_sumed = (float*)(ws + off);  off += (size_t)N_ATOMS * 64 * 4;
  float* part1 = (float*)(ws + off);      off += (size_t)NBLK_MAIN * 256 * 4;
  float* stats1 = (float*)(ws + off);     off += 256 * 4;
  float* part2 = (float*)(ws + off);      off += (size_t)NBLK_MAIN * 128 * 4;
  float* stats2 = (float*)(ws + off);     off += 128 * 4;
  unsigned* gated = (unsigned*)(ws + off);
  const size_t need_gated = off + (size_t)N_ATOMS * M_NBR * 64 * 4;
  const bool use_gated = (ws_size >= need_gated);

  k_transformer<<<B_CRY, 512, 0, stream>>>(atom_in, adj, w1, b1, w2, b2,
      tln1_g, tln1_b, tln2_g, tln2_b, cidx, fc_w, fc_b, atom_tf, proj1p, proj2p);
  if (use_gated){
    k_stats<1><<<NBLK_MAIN, 256, 0, stream>>>(nbr_fea, nbr_idx, fc_w, proj1p,
        proj2p, part1, gated);
    k_stats_fin<<<1, 1024, 0, stream>>>(part1, bn1_g, bn1_b, stats1);
    k_reduce_g<<<NBLK_MAIN, 256, 0, stream>>>(gated, stats1, nbr_sumed, part2);
  } else {
    k_stats<0><<<NBLK_MAIN, 256, 0, stream>>>(nbr_fea, nbr_idx, fc_w, proj1p,
        proj2p, part1, gated);
    k_stats_fin<<<1, 1024, 0, stream>>>(part1, bn1_g, bn1_b, stats1);
    k_reduce_r<<<NBLK_MAIN, 256, 0, stream>>>(nbr_fea, nbr_idx, fc_w, proj1p,
        proj2p, stats1, nbr_sumed, part2);
  }
  k_red_fin<<<1, 1024, 0, stream>>>(part2, bn2_g, bn2_b, stats2);
  k_final<<<(N_ATOMS * 64 + 255) / 256, 256, 0, stream>>>(atom_tf, nbr_sumed, stats2, out);
}

// Round 21
// 347.300 us; speedup vs baseline: 1.5551x; 1.5551x over previous
//
#include <hip/hip_runtime.h>
#include <math.h>

#define N_ATOMS 60000
#define M_NBR   12
#define D_FEA   64
#define NBR_FEA 41
#define B_CRY   1200
#define NA_CRY  50
#define EPSV    1e-5f

#define NBLK_MAIN 2048   // blocks for k_stats (4 waves each)

__device__ __forceinline__ float wsum(float v){
#pragma unroll
  for (int o = 32; o > 0; o >>= 1) v += __shfl_xor(v, o, 64);
  return v;
}
__device__ __forceinline__ float wmax64(float v){
#pragma unroll
  for (int o = 32; o > 0; o >>= 1) v = fmaxf(v, __shfl_xor(v, o, 64));
  return v;
}
__device__ __forceinline__ float softplusf(float x){
  return fmaxf(x, 0.f) + __logf(1.f + __expf(-fabsf(x)));
}
__device__ __forceinline__ float sigmoidf(float x){
  return 1.f / (1.f + __expf(-x));
}
// round-to-nearest-even fp32 -> bf16 bits (low 16)
__device__ __forceinline__ unsigned bf16_rne(float x){
  unsigned u = __float_as_uint(x);
  return (u + 0x7fffu + ((u >> 16) & 1u)) >> 16;
}
__device__ __forceinline__ unsigned pack2(float lo, float hi){
  return bf16_rne(lo) | (bf16_rne(hi) << 16);
}
__device__ __forceinline__ float unlo(unsigned u){ return __uint_as_float(u << 16); }
__device__ __forceinline__ float unhi(unsigned u){ return __uint_as_float(u & 0xffff0000u); }

// ---------------- K1: transformer + fused projections (r19/r20 proven) ------
__global__ __launch_bounds__(512, 4) void k_transformer(
    const float* __restrict__ atom_in, const float* __restrict__ adj,
    const float* __restrict__ w1, const float* __restrict__ b1,
    const float* __restrict__ w2, const float* __restrict__ b2,
    const float* __restrict__ g1v, const float* __restrict__ be1,
    const float* __restrict__ g2v, const float* __restrict__ be2,
    const int* __restrict__ cidx, const float* __restrict__ fc_w,
    const float* __restrict__ fc_b, float* __restrict__ atom_tf,
    unsigned* __restrict__ proj1p, unsigned* __restrict__ proj2p)
{
  __shared__ float s_a[NA_CRY * D_FEA];        // src / LN1 / LN2-out
  __shared__ float s_b[D_FEA * (NA_CRY + 1)];  // srcT(stride 51) / x
  __shared__ float s_c[NA_CRY * D_FEA];        // scores / h1 / atom_in rows
  __shared__ int   s_gi[NA_CRY];               // gathered atom ids

  const int tid  = threadIdx.x;
  const int b    = blockIdx.x;
  const int lane = tid & 63;
  const int w    = tid >> 6;   // 0..7

  // phase 1: load src (gather) + transposed copy (stride 51); stash ids
  if (tid < NA_CRY) s_gi[tid] = cidx[b * NA_CRY + tid];
  for (int p = tid; p < NA_CRY * D_FEA; p += 512){
    int i = p >> 6, d = p & 63;
    int a = cidx[b * NA_CRY + i];
    float v = atom_in[a * D_FEA + d];
    s_a[p] = v;
    s_b[d * (NA_CRY + 1) + i] = v;
  }
  __syncthreads();

  // phase 2: scores = (src . src^T) * scale * adj, 2x2 tile per thread
  const float scale = 0.125f; // 1/sqrt(64)
  {
    const float* adjb = adj + (size_t)b * NA_CRY * NA_CRY;
    for (int t = tid; t < 625; t += 512){
      int i0 = (t / 25) * 2, j0 = (t % 25) * 2;
      float a00 = 0.f, a01 = 0.f, a10 = 0.f, a11 = 0.f;
#pragma unroll 8
      for (int d = 0; d < D_FEA; ++d){
        float va0 = s_a[i0 * D_FEA + d];
        float va1 = s_a[(i0 + 1) * D_FEA + d];
        float vb0 = s_b[d * (NA_CRY + 1) + j0];
        float vb1 = s_b[d * (NA_CRY + 1) + j0 + 1];
        a00 += va0 * vb0; a01 += va0 * vb1;
        a10 += va1 * vb0; a11 += va1 * vb1;
      }
      s_c[i0 * NA_CRY + j0]           = a00 * scale * adjb[i0 * NA_CRY + j0];
      s_c[i0 * NA_CRY + j0 + 1]       = a01 * scale * adjb[i0 * NA_CRY + j0 + 1];
      s_c[(i0 + 1) * NA_CRY + j0]     = a10 * scale * adjb[(i0 + 1) * NA_CRY + j0];
      s_c[(i0 + 1) * NA_CRY + j0 + 1] = a11 * scale * adjb[(i0 + 1) * NA_CRY + j0 + 1];
    }
  }
  __syncthreads();

  // phase 3: softmax over rows (wave per row)
  for (int r = w; r < NA_CRY; r += 8){
    float v = (lane < NA_CRY) ? s_c[r * NA_CRY + lane] : -1e30f;
    float mx = wmax64(v);
    float e = (lane < NA_CRY) ? __expf(v - mx) : 0.f;
    float s = wsum(e);
    if (lane < NA_CRY) s_c[r * NA_CRY + lane] = e / s;
  }
  __syncthreads();

  // phase 4: x = src + attn @ src -> s_b; 2 rows/thread share s_a[m][d].
  for (int t = tid; t < 25 * D_FEA; t += 512){
    int nh = t >> 6, d = t & 63;
    int n0 = nh * 2, n1 = n0 + 1;
    float x0 = 0.f, x1 = 0.f;
#pragma unroll 10
    for (int m = 0; m < NA_CRY; ++m){
      float sa = s_a[m * D_FEA + d];
      x0 += s_c[n0 * NA_CRY + m] * sa;
      x1 += s_c[n1 * NA_CRY + m] * sa;
    }
    s_b[n0 * D_FEA + d] = s_a[n0 * D_FEA + d] + x0;
    s_b[n1 * D_FEA + d] = s_a[n1 * D_FEA + d] + x1;
  }
  __syncthreads();

  // phase 5: LN1 -> s_a
  for (int r = w; r < NA_CRY; r += 8){
    float x = s_b[r * D_FEA + lane];
    float mu = wsum(x) * (1.f / 64.f);
    float dx = x - mu;
    float var = wsum(dx * dx) * (1.f / 64.f);
    s_a[r * D_FEA + lane] = dx * rsqrtf(var + EPSV) * g1v[lane] + be1[lane];
  }
  __syncthreads();

  // phase 6: h1 = relu(LN1 @ w1 + b1) -> s_c  (2 rows x 2 k-parities)
  for (int n0 = w * 2; n0 < NA_CRY; n0 += 16){
    const int n1 = n0 + 1;
    float x00 = 0.f, x01 = 0.f, x10 = 0.f, x11 = 0.f;
#pragma unroll
    for (int k = 0; k < D_FEA; k += 2){
      float wv0 = w1[k * D_FEA + lane];
      float wv1 = w1[(k + 1) * D_FEA + lane];
      x00 += s_a[n0 * D_FEA + k] * wv0;
      x01 += s_a[n0 * D_FEA + k + 1] * wv1;
      x10 += s_a[n1 * D_FEA + k] * wv0;
      x11 += s_a[n1 * D_FEA + k + 1] * wv1;
    }
    float bb = b1[lane];
    s_c[n0 * D_FEA + lane] = fmaxf(bb + x00 + x01, 0.f);
    s_c[n1 * D_FEA + lane] = fmaxf(bb + x10 + x11, 0.f);
  }
  __syncthreads();

  // phase 7+8 fused: t = LN1 + h1 @ w2 + b2, then LN2 in-register
  for (int n0 = w * 2; n0 < NA_CRY; n0 += 16){
    const int n1 = n0 + 1;
    float x00 = 0.f, x01 = 0.f, x10 = 0.f, x11 = 0.f;
#pragma unroll
    for (int k = 0; k < D_FEA; k += 2){
      float wv0 = w2[k * D_FEA + lane];
      float wv1 = w2[(k + 1) * D_FEA + lane];
      x00 += s_c[n0 * D_FEA + k] * wv0;
      x01 += s_c[n0 * D_FEA + k + 1] * wv1;
      x10 += s_c[n1 * D_FEA + k] * wv0;
      x11 += s_c[n1 * D_FEA + k + 1] * wv1;
    }
    float bb = b2[lane];
    float t0 = s_a[n0 * D_FEA + lane] + bb + x00 + x01;
    float t1 = s_a[n1 * D_FEA + lane] + bb + x10 + x11;
    {
      float mu = wsum(t0) * (1.f / 64.f);
      float dx = t0 - mu;
      float var = wsum(dx * dx) * (1.f / 64.f);
      float res = dx * rsqrtf(var + EPSV) * g2v[lane] + be2[lane];
      atom_tf[(size_t)(b * NA_CRY + n0) * D_FEA + lane] = res;
      s_a[n0 * D_FEA + lane] = res;
    }
    {
      float mu = wsum(t1) * (1.f / 64.f);
      float dx = t1 - mu;
      float var = wsum(dx * dx) * (1.f / 64.f);
      float res = dx * rsqrtf(var + EPSV) * g2v[lane] + be2[lane];
      atom_tf[(size_t)(b * NA_CRY + n1) * D_FEA + lane] = res;
      s_a[n1 * D_FEA + lane] = res;
    }
  }
  __syncthreads();

  // phase 9a: re-gather atom_in rows into s_c (h1 dead)
  for (int p = tid; p < NA_CRY * D_FEA; p += 512){
    int i = p >> 6, d = p & 63;
    s_c[p] = atom_in[(size_t)s_gi[i] * D_FEA + d];
  }
  __syncthreads();

  // phase 9b: fused projections, 4 rows share each fc_w load quartet.
  for (int n0 = w * 4; n0 < NA_CRY; n0 += 32){
    const int nb = (n0 + 1 < NA_CRY) ? n0 + 1 : NA_CRY - 1;
    const int nc = (n0 + 2 < NA_CRY) ? n0 + 2 : NA_CRY - 1;
    const int nd = (n0 + 3 < NA_CRY) ? n0 + 3 : NA_CRY - 1;
    const int c = lane;
    const float bb0 = fc_b[c], bb1 = fc_b[64 + c];
    float A1 = bb0, A2 = bb1, A3 = 0.f, A4 = 0.f;
    float B1 = bb0, B2 = bb1, B3 = 0.f, B4 = 0.f;
    float C1 = bb0, C2 = bb1, C3 = 0.f, C4 = 0.f;
    float D1 = bb0, D2 = bb1, D3 = 0.f, D4 = 0.f;
#pragma unroll 4
    for (int k = 0; k < D_FEA; ++k){
      float w0 = fc_w[k * 128 + c];
      float w6 = fc_w[k * 128 + 64 + c];
      float v0 = fc_w[(64 + k) * 128 + c];
      float v6 = fc_w[(64 + k) * 128 + 64 + c];
      float ta = s_a[n0 * 64 + k], tb = s_a[nb * 64 + k];
      float tc = s_a[nc * 64 + k], td = s_a[nd * 64 + k];
      float sa = s_c[n0 * 64 + k], sb = s_c[nb * 64 + k];
      float sc = s_c[nc * 64 + k], sd = s_c[nd * 64 + k];
      A1 += ta * w0; A2 += ta * w6; A3 += sa * v0; A4 += sa * v6;
      B1 += tb * w0; B2 += tb * w6; B3 += sb * v0; B4 += sb * v6;
      C1 += tc * w0; C2 += tc * w6; C3 += sc * v0; C4 += sc * v6;
      D1 += td * w0; D2 += td * w6; D3 += sd * v0; D4 += sd * v6;
    }
    proj1p[(size_t)(b * NA_CRY + n0) * 64 + c] = pack2(A1, A2);
    proj2p[(size_t)s_gi[n0] * 64 + c] = pack2(A3, A4);
    if (n0 + 1 < NA_CRY){
      proj1p[(size_t)(b * NA_CRY + nb) * 64 + c] = pack2(B1, B2);
      proj2p[(size_t)s_gi[nb] * 64 + c] = pack2(B3, B4);
    }
    if (n0 + 2 < NA_CRY){
      proj1p[(size_t)(b * NA_CRY + nc) * 64 + c] = pack2(C1, C2);
      proj2p[(size_t)s_gi[nc] * 64 + c] = pack2(C3, C4);
    }
    if (n0 + 3 < NA_CRY){
      proj1p[(size_t)(b * NA_CRY + nd) * 64 + c] = pack2(D1, D2);
      proj2p[(size_t)s_gi[nd] * 64 + c] = pack2(D3, D4);
    }
  }
}

// ---------------- K3: BN1 stats + store pre-BN g (bf16x2) -------------------
// r16-proven structure; 16B global_load_lds staging (r19).
#define LOADRW(MM) unsigned rw##MM = proj2p[(size_t)__builtin_amdgcn_readfirstlane(jrow[MM]) * 64 + lane];

#define STAGE(AA, BUF) { \
    const float* srcp = nbr_fea + (size_t)(AA) * (M_NBR * NBR_FEA); \
    float* dstp = s_frow + (w * 2 + (BUF)) * 512; \
    __builtin_amdgcn_global_load_lds(srcp + lane * 4, dstp, 16, 0, 0); \
    if (lane < 59) \
      __builtin_amdgcn_global_load_lds(srcp + 256 + lane * 4, dstp + 256, 16, 0, 0); \
  }

#define GBODY(MM) { \
    float g0 = p10 + unlo(rw##MM); \
    float g1 = p11 + unhi(rw##MM); \
    _Pragma("unroll") \
    for (int k = 0; k < NBR_FEA; ++k){ \
      float aa = fr[MM * NBR_FEA + k]; \
      g0 += aa * unlo(wbp[k]); \
      g1 += aa * unhi(wbp[k]); \
    } \
    if (STORE) gated[(size_t)(base + MM) * 64 + lane] = pack2(g0, g1); \
    s0 += g0; q0 += g0 * g0; \
    s1 += g1; q1 += g1 * g1; }

template<int STORE>
__global__ __launch_bounds__(256) void k_stats(
    const float* __restrict__ nbr_fea, const int* __restrict__ nbr_idx,
    const float* __restrict__ fc_w, const unsigned* __restrict__ proj1p,
    const unsigned* __restrict__ proj2p, float* __restrict__ part1,
    unsigned* __restrict__ gated)
{
  __shared__ float red[1024];
  __shared__ float s_frow[4 * 2 * 512];  // 4 waves x double-buffer x 512 floats
  const int tid = threadIdx.x, lane = tid & 63, w = tid >> 6;

  unsigned wbp[NBR_FEA];
#pragma unroll
  for (int k = 0; k < NBR_FEA; ++k){
    float w0 = fc_w[(128 + k) * 128 + lane];
    float w1 = fc_w[(128 + k) * 128 + 64 + lane];
    wbp[k] = pack2(w0, w1);
  }

  const int gw = blockIdx.x * 4 + w, nw = gridDim.x * 4;
  const int q = N_ATOMS / nw, rr = N_ATOMS % nw;
  const int a0 = gw * q + (gw < rr ? gw : rr);
  const int a1 = a0 + q + (gw < rr ? 1 : 0);
  float s0 = 0.f, s1 = 0.f, q0 = 0.f, q1 = 0.f;
  int cur = 0;
  if (a0 < a1){ STAGE(a0, 0); }
  for (int a = a0; a < a1; ++a){
    const int au = __builtin_amdgcn_readfirstlane(a);
    const int base = au * M_NBR;
    const int* jrow = nbr_idx + base;            // uniform -> s_load (tiny)
    unsigned p1v = proj1p[(size_t)au * 64 + lane];
    LOADRW(0) LOADRW(1) LOADRW(2) LOADRW(3) LOADRW(4) LOADRW(5)
    LOADRW(6) LOADRW(7) LOADRW(8) LOADRW(9) LOADRW(10) LOADRW(11)
    const int anext = (a + 1 < a1) ? (a + 1) : a;
    STAGE(anext, cur ^ 1);                       // 2 newest vmem ops
    asm volatile("s_waitcnt vmcnt(2)" ::: "memory");  // drain rw/p1 + prior stage
    const float* fr = s_frow + (w * 2 + cur) * 512;
    const float p10 = unlo(p1v), p11 = unhi(p1v);
    GBODY(0) GBODY(1) GBODY(2) GBODY(3) GBODY(4) GBODY(5)
    GBODY(6) GBODY(7) GBODY(8) GBODY(9) GBODY(10) GBODY(11)
    cur ^= 1;
  }
  red[w * 256 + lane]        = s0;
  red[w * 256 + 64 + lane]   = s1;
  red[w * 256 + 128 + lane]  = q0;
  red[w * 256 + 192 + lane]  = q1;
  __syncthreads();
  float v = red[tid] + red[256 + tid] + red[512 + tid] + red[768 + tid];
  part1[blockIdx.x * 256 + tid] = v;   // [0:128]=sum(ch), [128:256]=sumsq(ch)
}

// ---- parallel BN1 finish: 128 blocks, block c reduces slots c & 128+c ------
// (r20 diagnosis: single-block fin reads 2MB scattered across 8 XCD L2s with
// 16 waves -> latency-serialized, plausibly 50-100us hidden. 128x256 threads
// hide it fully.)
__global__ __launch_bounds__(256) void k_stats_fin(
    const float* __restrict__ part1, const float* __restrict__ bn1_g,
    const float* __restrict__ bn1_b, float* __restrict__ stats1)
{
  __shared__ float red[256];
  const int c = blockIdx.x;      // 0..127 (channel)
  const int t = threadIdx.x;     // 0..255
  float s = 0.f, q = 0.f;
#pragma unroll
  for (int i = t; i < NBLK_MAIN; i += 256){
    s += part1[(size_t)i * 256 + c];
    q += part1[(size_t)i * 256 + 128 + c];
  }
  red[t] = s; __syncthreads();
  for (int o = 128; o > 0; o >>= 1){ if (t < o) red[t] += red[t + o]; __syncthreads(); }
  float sumv = red[0]; __syncthreads();
  red[t] = q; __syncthreads();
  for (int o = 128; o > 0; o >>= 1){ if (t < o) red[t] += red[t + o]; __syncthreads(); }
  if (t == 0){
    const float inv = 1.f / (float)(N_ATOMS * M_NBR);
    float mu = sumv * inv;
    float var = red[0] * inv - mu * mu;
    float sc = bn1_g[c] * rsqrtf(var + EPSV);
    stats1[c] = sc;
    stats1[128 + c] = bn1_b[c] - mu * sc;
  }
}

// ---------------- K4a (gated path): streaming BN1+gate+sum ------------------
__global__ __launch_bounds__(256) void k_reduce_g(
    const unsigned* __restrict__ gated, const float* __restrict__ stats1,
    float* __restrict__ nbr_sumed, float* __restrict__ part2)
{
  __shared__ float red[512];
  const int tid = threadIdx.x, lane = tid & 63, w = tid >> 6;
  const float sc0 = stats1[lane],       sc1 = stats1[64 + lane];
  const float tc0 = stats1[128 + lane], tc1 = stats1[192 + lane];
  const int wg = blockIdx.x * 4 + w, nw = gridDim.x * 4;
  float bs = 0.f, bq = 0.f;
  for (int a = wg; a < N_ATOMS; a += nw){
    const size_t base = (size_t)a * M_NBR * 64 + lane;
    float acc = 0.f;
#pragma unroll
    for (int m = 0; m < M_NBR; ++m){
      unsigned gv = gated[base + m * 64];
      acc += sigmoidf(unlo(gv) * sc0 + tc0) * softplusf(unhi(gv) * sc1 + tc1);
    }
    nbr_sumed[(size_t)a * 64 + lane] = acc;
    bs += acc; bq += acc * acc;
  }
  red[w * 128 + lane]      = bs;
  red[w * 128 + 64 + lane] = bq;
  __syncthreads();
  if (tid < 128){
    float v = red[tid] + red[128 + tid] + red[256 + tid] + red[384 + tid];
    part2[blockIdx.x * 128 + tid] = v;  // [0:64]=sum, [64:128]=sumsq
  }
}

// ---------------- K4b (fallback): recompute g, BN1, gate, sum ---------------
#define GBODYR(MM) { \
    const float* frow = nbr_fea + (size_t)(base + MM) * NBR_FEA; \
    float g0 = p10 + unlo(rw##MM); \
    float g1 = p11 + unhi(rw##MM); \
    _Pragma("unroll") \
    for (int k = 0; k < NBR_FEA; ++k){ \
      float aa = frow[k]; \
      g0 += aa * unlo(wbp[k]); \
      g1 += aa * unhi(wbp[k]); \
    } \
    acc += sigmoidf(g0 * sc0 + tc0) * softplusf(g1 * sc1 + tc1); }

__global__ __launch_bounds__(256) void k_reduce_r(
    const float* __restrict__ nbr_fea, const int* __restrict__ nbr_idx,
    const float* __restrict__ fc_w, const unsigned* __restrict__ proj1p,
    const unsigned* __restrict__ proj2p, const float* __restrict__ stats1,
    float* __restrict__ nbr_sumed, float* __restrict__ part2)
{
  __shared__ float red[512];
  const int tid = threadIdx.x, lane = tid & 63, w = tid >> 6;
  unsigned wbp[NBR_FEA];
#pragma unroll
  for (int k = 0; k < NBR_FEA; ++k){
    float w0 = fc_w[(128 + k) * 128 + lane];
    float w1 = fc_w[(128 + k) * 128 + 64 + lane];
    wbp[k] = pack2(w0, w1);
  }
  const float sc0 = stats1[lane],       sc1 = stats1[64 + lane];
  const float tc0 = stats1[128 + lane], tc1 = stats1[192 + lane];
  const int gw = blockIdx.x * 4 + w, nw = gridDim.x * 4;
  const int q = N_ATOMS / nw, rr = N_ATOMS % nw;
  const int a0 = gw * q + (gw < rr ? gw : rr);
  const int a1 = a0 + q + (gw < rr ? 1 : 0);
  float bs = 0.f, bq = 0.f;
  for (int a = a0; a < a1; ++a){
    const int au = __builtin_amdgcn_readfirstlane(a);
    const int base = au * M_NBR;
    const int* jrow = nbr_idx + base;
    unsigned p1v = proj1p[(size_t)au * 64 + lane];
    LOADRW(0) LOADRW(1) LOADRW(2) LOADRW(3) LOADRW(4) LOADRW(5)
    LOADRW(6) LOADRW(7) LOADRW(8) LOADRW(9) LOADRW(10) LOADRW(11)
    const float p10 = unlo(p1v), p11 = unhi(p1v);
    float acc = 0.f;
    GBODYR(0) GBODYR(1) GBODYR(2) GBODYR(3) GBODYR(4) GBODYR(5)
    GBODYR(6) GBODYR(7) GBODYR(8) GBODYR(9) GBODYR(10) GBODYR(11)
    nbr_sumed[(size_t)au * 64 + lane] = acc;
    bs += acc; bq += acc * acc;
  }
  red[w * 128 + lane]      = bs;
  red[w * 128 + 64 + lane] = bq;
  __syncthreads();
  if (tid < 128){
    float v = red[tid] + red[128 + tid] + red[256 + tid] + red[384 + tid];
    part2[blockIdx.x * 128 + tid] = v;
  }
}

// ---- parallel BN2 finish: 64 blocks, block c reduces slots c & 64+c --------
__global__ __launch_bounds__(256) void k_red_fin(
    const float* __restrict__ part2, const float* __restrict__ bn2_g,
    const float* __restrict__ bn2_b, float* __restrict__ stats2)
{
  __shared__ float red[256];
  const int c = blockIdx.x;      // 0..63
  const int t = threadIdx.x;
  float s = 0.f, q = 0.f;
#pragma unroll
  for (int i = t; i < NBLK_MAIN; i += 256){
    s += part2[(size_t)i * 128 + c];
    q += part2[(size_t)i * 128 + 64 + c];
  }
  red[t] = s; __syncthreads();
  for (int o = 128; o > 0; o >>= 1){ if (t < o) red[t] += red[t + o]; __syncthreads(); }
  float sumv = red[0]; __syncthreads();
  red[t] = q; __syncthreads();
  for (int o = 128; o > 0; o >>= 1){ if (t < o) red[t] += red[t + o]; __syncthreads(); }
  if (t == 0){
    const float inv = 1.f / (float)N_ATOMS;
    float mu = sumv * inv;
    float var = red[0] * inv - mu * mu;
    float sc = bn2_g[c] * rsqrtf(var + EPSV);
    stats2[c] = sc;
    stats2[64 + c] = bn2_b[c] - mu * sc;
  }
}

// ---------------- K5: out = softplus(atom_tf + BN2(nbr_sumed)) --------------
__global__ __launch_bounds__(256) void k_final(
    const float* __restrict__ atom_tf, const float* __restrict__ ns,
    const float* __restrict__ stats2, float* __restrict__ out)
{
  int i = blockIdx.x * 256 + threadIdx.x;
  if (i >= N_ATOMS * 64) return;
  int c = i & 63;
  float x = atom_tf[i] + ns[i] * stats2[c] + stats2[64 + c];
  out[i] = softplusf(x);
}

extern "C" void kernel_launch(void* const* d_in, const int* in_sizes, int n_in,
                              void* d_out, int out_size, void* d_ws, size_t ws_size,
                              hipStream_t stream)
{
  const float* atom_in = (const float*)d_in[0];
  const float* nbr_fea = (const float*)d_in[1];
  const float* adj     = (const float*)d_in[2];
  const float* w1 = (const float*)d_in[3];
  const float* b1 = (const float*)d_in[4];
  const float* w2 = (const float*)d_in[5];
  const float* b2 = (const float*)d_in[6];
  const float* tln1_g = (const float*)d_in[7];
  const float* tln1_b = (const float*)d_in[8];
  const float* tln2_g = (const float*)d_in[9];
  const float* tln2_b = (const float*)d_in[10];
  const float* fc_w = (const float*)d_in[11];
  const float* fc_b = (const float*)d_in[12];
  const float* bn1_g = (const float*)d_in[13];
  const float* bn1_b = (const float*)d_in[14];
  const float* bn2_g = (const float*)d_in[15];
  const float* bn2_b = (const float*)d_in[16];
  const int* nbr_idx = (const int*)d_in[17];
  const int* cidx    = (const int*)d_in[18];
  float* out = (float*)d_out;

  char* ws = (char*)d_ws;
  size_t off = 0;
  float* atom_tf = (float*)(ws + off);    off += (size_t)N_ATOMS * 64 * 4;
  unsigned* proj1p = (unsigned*)(ws + off); off += (size_t)N_ATOMS * 64 * 4;
  unsigned* proj2p = (unsigned*)(ws + off); off += (size_t)N_ATOMS * 64 * 4;
  float* nbr_sumed = (float*)(ws + off);  off += (size_t)N_ATOMS * 64 * 4;
  float* part1 = (float*)(ws + off);      off += (size_t)NBLK_MAIN * 256 * 4;
  float* stats1 = (float*)(ws + off);     off += 256 * 4;
  float* part2 = (float*)(ws + off);      off += (size_t)NBLK_MAIN * 128 * 4;
  float* stats2 = (float*)(ws + off);     off += 128 * 4;
  unsigned* gated = (unsigned*)(ws + off);
  const size_t need_gated = off + (size_t)N_ATOMS * M_NBR * 64 * 4;
  const bool use_gated = (ws_size >= need_gated);

  k_transformer<<<B_CRY, 512, 0, stream>>>(atom_in, adj, w1, b1, w2, b2,
      tln1_g, tln1_b, tln2_g, tln2_b, cidx, fc_w, fc_b, atom_tf, proj1p, proj2p);
  if (use_gated){
    k_stats<1><<<NBLK_MAIN, 256, 0, stream>>>(nbr_fea, nbr_idx, fc_w, proj1p,
        proj2p, part1, gated);
    k_stats_fin<<<128, 256, 0, stream>>>(part1, bn1_g, bn1_b, stats1);
    k_reduce_g<<<NBLK_MAIN, 256, 0, stream>>>(gated, stats1, nbr_sumed, part2);
  } else {
    k_stats<0><<<NBLK_MAIN, 256, 0, stream>>>(nbr_fea, nbr_idx, fc_w, proj1p,
        proj2p, part1, gated);
    k_stats_fin<<<128, 256, 0, stream>>>(part1, bn1_g, bn1_b, stats1);
    k_reduce_r<<<NBLK_MAIN, 256, 0, stream>>>(nbr_fea, nbr_idx, fc_w, proj1p,
        proj2p, stats1, nbr_sumed, part2);
  }
  k_red_fin<<<64, 256, 0, stream>>>(part2, bn2_g, bn2_b, stats2);
  k_final<<<(N_ATOMS * 64 + 255) / 256, 256, 0, stream>>>(atom_tf, nbr_sumed, stats2, out);
}

// Round 22
// 341.292 us; speedup vs baseline: 1.5825x; 1.0176x over previous
//
#include <hip/hip_runtime.h>
#include <math.h>

#define N_ATOMS 60000
#define M_NBR   12
#define D_FEA   64
#define NBR_FEA 41
#define B_CRY   1200
#define NA_CRY  50
#define EPSV    1e-5f

#define NBLK_MAIN 2048   // blocks for k_stats (4 waves each)

__device__ __forceinline__ float wsum(float v){
#pragma unroll
  for (int o = 32; o > 0; o >>= 1) v += __shfl_xor(v, o, 64);
  return v;
}
__device__ __forceinline__ float wmax64(float v){
#pragma unroll
  for (int o = 32; o > 0; o >>= 1) v = fmaxf(v, __shfl_xor(v, o, 64));
  return v;
}
__device__ __forceinline__ float softplusf(float x){
  return fmaxf(x, 0.f) + __logf(1.f + __expf(-fabsf(x)));
}
__device__ __forceinline__ float sigmoidf(float x){
  return 1.f / (1.f + __expf(-x));
}
// round-to-nearest-even fp32 -> bf16 bits (low 16)
__device__ __forceinline__ unsigned bf16_rne(float x){
  unsigned u = __float_as_uint(x);
  return (u + 0x7fffu + ((u >> 16) & 1u)) >> 16;
}
__device__ __forceinline__ unsigned pack2(float lo, float hi){
  return bf16_rne(lo) | (bf16_rne(hi) << 16);
}
__device__ __forceinline__ float unlo(unsigned u){ return __uint_as_float(u << 16); }
__device__ __forceinline__ float unhi(unsigned u){ return __uint_as_float(u & 0xffff0000u); }

// ---------------- K1a: attention half (phases 1-5) -> ln1 [N,64] ------------
// r21 diagnosis: monolithic transformer = 9 serialized phases, occupancy 37%.
// Split: this kernel keeps only the crystal-wide part (attention + LN1);
// the per-row FF/proj half moves to barrier-free k_ff. ln1 aliases the
// nbr_sumed ws buffer (not used until k_reduce_g, well after k_ff).
__global__ __launch_bounds__(512, 4) void k_attn(
    const float* __restrict__ atom_in, const float* __restrict__ adj,
    const float* __restrict__ g1v, const float* __restrict__ be1,
    const int* __restrict__ cidx, float* __restrict__ ln1)
{
  __shared__ float s_a[NA_CRY * D_FEA];        // src rows
  __shared__ float s_b[D_FEA * (NA_CRY + 1)];  // srcT(stride 51) / x
  __shared__ float s_c[NA_CRY * D_FEA];        // scores

  const int tid  = threadIdx.x;
  const int b    = blockIdx.x;
  const int lane = tid & 63;
  const int w    = tid >> 6;   // 0..7

  // phase 1: load src (gather) + transposed copy (stride 51)
  for (int p = tid; p < NA_CRY * D_FEA; p += 512){
    int i = p >> 6, d = p & 63;
    int a = cidx[b * NA_CRY + i];
    float v = atom_in[(size_t)a * D_FEA + d];
    s_a[p] = v;
    s_b[d * (NA_CRY + 1) + i] = v;
  }
  __syncthreads();

  // phase 2: scores = (src . src^T) * scale * adj, 2x2 tile per thread
  const float scale = 0.125f; // 1/sqrt(64)
  {
    const float* adjb = adj + (size_t)b * NA_CRY * NA_CRY;
    for (int t = tid; t < 625; t += 512){
      int i0 = (t / 25) * 2, j0 = (t % 25) * 2;
      float a00 = 0.f, a01 = 0.f, a10 = 0.f, a11 = 0.f;
#pragma unroll 8
      for (int d = 0; d < D_FEA; ++d){
        float va0 = s_a[i0 * D_FEA + d];
        float va1 = s_a[(i0 + 1) * D_FEA + d];
        float vb0 = s_b[d * (NA_CRY + 1) + j0];
        float vb1 = s_b[d * (NA_CRY + 1) + j0 + 1];
        a00 += va0 * vb0; a01 += va0 * vb1;
        a10 += va1 * vb0; a11 += va1 * vb1;
      }
      s_c[i0 * NA_CRY + j0]           = a00 * scale * adjb[i0 * NA_CRY + j0];
      s_c[i0 * NA_CRY + j0 + 1]       = a01 * scale * adjb[i0 * NA_CRY + j0 + 1];
      s_c[(i0 + 1) * NA_CRY + j0]     = a10 * scale * adjb[(i0 + 1) * NA_CRY + j0];
      s_c[(i0 + 1) * NA_CRY + j0 + 1] = a11 * scale * adjb[(i0 + 1) * NA_CRY + j0 + 1];
    }
  }
  __syncthreads();

  // phase 3: softmax over rows (wave per row)
  for (int r = w; r < NA_CRY; r += 8){
    float v = (lane < NA_CRY) ? s_c[r * NA_CRY + lane] : -1e30f;
    float mx = wmax64(v);
    float e = (lane < NA_CRY) ? __expf(v - mx) : 0.f;
    float s = wsum(e);
    if (lane < NA_CRY) s_c[r * NA_CRY + lane] = e / s;
  }
  __syncthreads();

  // phase 4: x = src + attn @ src -> s_b; 2 rows/thread share s_a[m][d]
  for (int t = tid; t < 25 * D_FEA; t += 512){
    int nh = t >> 6, d = t & 63;
    int n0 = nh * 2, n1 = n0 + 1;
    float x0 = 0.f, x1 = 0.f;
#pragma unroll 10
    for (int m = 0; m < NA_CRY; ++m){
      float sa = s_a[m * D_FEA + d];
      x0 += s_c[n0 * NA_CRY + m] * sa;
      x1 += s_c[n1 * NA_CRY + m] * sa;
    }
    s_b[n0 * D_FEA + d] = s_a[n0 * D_FEA + d] + x0;
    s_b[n1 * D_FEA + d] = s_a[n1 * D_FEA + d] + x1;
  }
  __syncthreads();

  // phase 5: LN1 -> ln1 (global; per-row, wave per row)
  for (int r = w; r < NA_CRY; r += 8){
    float x = s_b[r * D_FEA + lane];
    float mu = wsum(x) * (1.f / 64.f);
    float dx = x - mu;
    float var = wsum(dx * dx) * (1.f / 64.f);
    ln1[(size_t)(b * NA_CRY + r) * D_FEA + lane] =
        dx * rsqrtf(var + EPSV) * g1v[lane] + be1[lane];
  }
}

// ---------------- K1b: FF + LN2 + projections, barrier-free -----------------
// wave = row (lane = channel); 4 rows per wave-iteration share each weight
// load; k-broadcasts via wave-private LDS slots (A[4],B[4] per wave = 2KB).
// No __syncthreads anywhere -> full latency hiding at ~8KB LDS/block.
__global__ __launch_bounds__(256) void k_ff(
    const float* __restrict__ ln1, const float* __restrict__ atom_in,
    const int* __restrict__ cidx,
    const float* __restrict__ w1, const float* __restrict__ b1,
    const float* __restrict__ w2, const float* __restrict__ b2,
    const float* __restrict__ g2v, const float* __restrict__ be2,
    const float* __restrict__ fc_w, const float* __restrict__ fc_b,
    float* __restrict__ atom_tf, unsigned* __restrict__ proj1p,
    unsigned* __restrict__ proj2p)
{
  __shared__ float sl[4][8][64];   // per wave: slots A0..3 (ln->res), B0..3 (h->s)
  const int tid = threadIdx.x, lane = tid & 63, w = tid >> 6;
  float (*A)[64] = &sl[w][0];      // slots 0..3
  float (*Bs)[64] = &sl[w][4];     // slots 4..7

  const int gw = blockIdx.x * 4 + w, nw = gridDim.x * 4;
  const int NGRP = N_ATOMS / 4;    // 15000
  for (int g = gw; g < NGRP; g += nw){
    const int r0 = g * 4;
    // load ln rows, stage to A
    float ln0 = ln1[(size_t)(r0 + 0) * 64 + lane];
    float ln1v = ln1[(size_t)(r0 + 1) * 64 + lane];
    float ln2 = ln1[(size_t)(r0 + 2) * 64 + lane];
    float ln3 = ln1[(size_t)(r0 + 3) * 64 + lane];
    A[0][lane] = ln0; A[1][lane] = ln1v; A[2][lane] = ln2; A[3][lane] = ln3;
    __builtin_amdgcn_s_waitcnt(0);   // lgkmcnt(0)+vmcnt(0): slots visible

    // FF1: h_j = relu(b1 + sum_k A[j][k] * w1[k][c])
    float h0a = 0.f, h1a = 0.f, h2a = 0.f, h3a = 0.f;
    float h0b = 0.f, h1b = 0.f, h2b = 0.f, h3b = 0.f;
#pragma unroll 8
    for (int k = 0; k < D_FEA; k += 2){
      float wv0 = w1[k * D_FEA + lane];
      float wv1 = w1[(k + 1) * D_FEA + lane];
      h0a += A[0][k] * wv0; h0b += A[0][k + 1] * wv1;
      h1a += A[1][k] * wv0; h1b += A[1][k + 1] * wv1;
      h2a += A[2][k] * wv0; h2b += A[2][k + 1] * wv1;
      h3a += A[3][k] * wv0; h3b += A[3][k + 1] * wv1;
    }
    float bb1 = b1[lane];
    float h0 = fmaxf(bb1 + h0a + h0b, 0.f);
    float h1 = fmaxf(bb1 + h1a + h1b, 0.f);
    float h2 = fmaxf(bb1 + h2a + h2b, 0.f);
    float h3 = fmaxf(bb1 + h3a + h3b, 0.f);
    Bs[0][lane] = h0; Bs[1][lane] = h1; Bs[2][lane] = h2; Bs[3][lane] = h3;
    __builtin_amdgcn_s_waitcnt(0);

    // FF2: t_j = ln_j + b2 + sum_k B[j][k] * w2[k][c]
    float t0a = 0.f, t1a = 0.f, t2a = 0.f, t3a = 0.f;
    float t0b = 0.f, t1b = 0.f, t2b = 0.f, t3b = 0.f;
#pragma unroll 8
    for (int k = 0; k < D_FEA; k += 2){
      float wv0 = w2[k * D_FEA + lane];
      float wv1 = w2[(k + 1) * D_FEA + lane];
      t0a += Bs[0][k] * wv0; t0b += Bs[0][k + 1] * wv1;
      t1a += Bs[1][k] * wv0; t1b += Bs[1][k + 1] * wv1;
      t2a += Bs[2][k] * wv0; t2b += Bs[2][k + 1] * wv1;
      t3a += Bs[3][k] * wv0; t3b += Bs[3][k + 1] * wv1;
    }
    float bb2 = b2[lane];
    float t0 = ln0 + bb2 + t0a + t0b;
    float t1 = ln1v + bb2 + t1a + t1b;
    float t2 = ln2 + bb2 + t2a + t2b;
    float t3 = ln3 + bb2 + t3a + t3b;

    // LN2 per row -> atom_tf + A slots
    float gv = g2v[lane], bv = be2[lane];
#define LN2ROW(TT, JJ) { \
      float mu = wsum(TT) * (1.f / 64.f); \
      float dx = (TT) - mu; \
      float var = wsum(dx * dx) * (1.f / 64.f); \
      float res = dx * rsqrtf(var + EPSV) * gv + bv; \
      atom_tf[(size_t)(r0 + JJ) * 64 + lane] = res; \
      A[JJ][lane] = res; }
    LN2ROW(t0, 0) LN2ROW(t1, 1) LN2ROW(t2, 2) LN2ROW(t3, 3)
#undef LN2ROW

    // gather atom_in rows -> B slots
    const int ga0 = cidx[r0], ga1 = cidx[r0 + 1], ga2 = cidx[r0 + 2], ga3 = cidx[r0 + 3];
    Bs[0][lane] = atom_in[(size_t)ga0 * 64 + lane];
    Bs[1][lane] = atom_in[(size_t)ga1 * 64 + lane];
    Bs[2][lane] = atom_in[(size_t)ga2 * 64 + lane];
    Bs[3][lane] = atom_in[(size_t)ga3 * 64 + lane];
    __builtin_amdgcn_s_waitcnt(0);

    // projections: 4 rows share each fc_w quartet
    const float bb0 = fc_b[lane], bb6 = fc_b[64 + lane];
    float A1 = bb0, A2 = bb6, A3 = 0.f, A4 = 0.f;
    float B1 = bb0, B2 = bb6, B3 = 0.f, B4 = 0.f;
    float C1 = bb0, C2 = bb6, C3 = 0.f, C4 = 0.f;
    float D1 = bb0, D2 = bb6, D3 = 0.f, D4 = 0.f;
#pragma unroll 4
    for (int k = 0; k < D_FEA; ++k){
      float w0 = fc_w[k * 128 + lane];
      float w6 = fc_w[k * 128 + 64 + lane];
      float v0 = fc_w[(64 + k) * 128 + lane];
      float v6 = fc_w[(64 + k) * 128 + 64 + lane];
      float ta = A[0][k], tb = A[1][k], tc = A[2][k], td = A[3][k];
      float sa = Bs[0][k], sb = Bs[1][k], sc = Bs[2][k], sd = Bs[3][k];
      A1 += ta * w0; A2 += ta * w6; A3 += sa * v0; A4 += sa * v6;
      B1 += tb * w0; B2 += tb * w6; B3 += sb * v0; B4 += sb * v6;
      C1 += tc * w0; C2 += tc * w6; C3 += sc * v0; C4 += sc * v6;
      D1 += td * w0; D2 += td * w6; D3 += sd * v0; D4 += sd * v6;
    }
    proj1p[(size_t)(r0 + 0) * 64 + lane] = pack2(A1, A2);
    proj1p[(size_t)(r0 + 1) * 64 + lane] = pack2(B1, B2);
    proj1p[(size_t)(r0 + 2) * 64 + lane] = pack2(C1, C2);
    proj1p[(size_t)(r0 + 3) * 64 + lane] = pack2(D1, D2);
    proj2p[(size_t)ga0 * 64 + lane] = pack2(A3, A4);
    proj2p[(size_t)ga1 * 64 + lane] = pack2(B3, B4);
    proj2p[(size_t)ga2 * 64 + lane] = pack2(C3, C4);
    proj2p[(size_t)ga3 * 64 + lane] = pack2(D3, D4);
  }
}

// ---------------- K3: BN1 stats + store pre-BN g (bf16x2) -------------------
#define LOADRW(MM) unsigned rw##MM = proj2p[(size_t)__builtin_amdgcn_readfirstlane(jrow[MM]) * 64 + lane];

#define STAGE(AA, BUF) { \
    const float* srcp = nbr_fea + (size_t)(AA) * (M_NBR * NBR_FEA); \
    float* dstp = s_frow + (w * 2 + (BUF)) * 512; \
    __builtin_amdgcn_global_load_lds(srcp + lane * 4, dstp, 16, 0, 0); \
    if (lane < 59) \
      __builtin_amdgcn_global_load_lds(srcp + 256 + lane * 4, dstp + 256, 16, 0, 0); \
  }

#define GBODY(MM) { \
    float g0 = p10 + unlo(rw##MM); \
    float g1 = p11 + unhi(rw##MM); \
    _Pragma("unroll") \
    for (int k = 0; k < NBR_FEA; ++k){ \
      float aa = fr[MM * NBR_FEA + k]; \
      g0 += aa * unlo(wbp[k]); \
      g1 += aa * unhi(wbp[k]); \
    } \
    if (STORE) gated[(size_t)(base + MM) * 64 + lane] = pack2(g0, g1); \
    s0 += g0; q0 += g0 * g0; \
    s1 += g1; q1 += g1 * g1; }

template<int STORE>
__global__ __launch_bounds__(256) void k_stats(
    const float* __restrict__ nbr_fea, const int* __restrict__ nbr_idx,
    const float* __restrict__ fc_w, const unsigned* __restrict__ proj1p,
    const unsigned* __restrict__ proj2p, float* __restrict__ part1,
    unsigned* __restrict__ gated)
{
  __shared__ float red[1024];
  __shared__ float s_frow[4 * 2 * 512];
  const int tid = threadIdx.x, lane = tid & 63, w = tid >> 6;

  unsigned wbp[NBR_FEA];
#pragma unroll
  for (int k = 0; k < NBR_FEA; ++k){
    float w0 = fc_w[(128 + k) * 128 + lane];
    float w1 = fc_w[(128 + k) * 128 + 64 + lane];
    wbp[k] = pack2(w0, w1);
  }

  const int gw = blockIdx.x * 4 + w, nw = gridDim.x * 4;
  const int q = N_ATOMS / nw, rr = N_ATOMS % nw;
  const int a0 = gw * q + (gw < rr ? gw : rr);
  const int a1 = a0 + q + (gw < rr ? 1 : 0);
  float s0 = 0.f, s1 = 0.f, q0 = 0.f, q1 = 0.f;
  int cur = 0;
  if (a0 < a1){ STAGE(a0, 0); }
  for (int a = a0; a < a1; ++a){
    const int au = __builtin_amdgcn_readfirstlane(a);
    const int base = au * M_NBR;
    const int* jrow = nbr_idx + base;
    unsigned p1v = proj1p[(size_t)au * 64 + lane];
    LOADRW(0) LOADRW(1) LOADRW(2) LOADRW(3) LOADRW(4) LOADRW(5)
    LOADRW(6) LOADRW(7) LOADRW(8) LOADRW(9) LOADRW(10) LOADRW(11)
    const int anext = (a + 1 < a1) ? (a + 1) : a;
    STAGE(anext, cur ^ 1);
    asm volatile("s_waitcnt vmcnt(2)" ::: "memory");
    const float* fr = s_frow + (w * 2 + cur) * 512;
    const float p10 = unlo(p1v), p11 = unhi(p1v);
    GBODY(0) GBODY(1) GBODY(2) GBODY(3) GBODY(4) GBODY(5)
    GBODY(6) GBODY(7) GBODY(8) GBODY(9) GBODY(10) GBODY(11)
    cur ^= 1;
  }
  red[w * 256 + lane]        = s0;
  red[w * 256 + 64 + lane]   = s1;
  red[w * 256 + 128 + lane]  = q0;
  red[w * 256 + 192 + lane]  = q1;
  __syncthreads();
  float v = red[tid] + red[256 + tid] + red[512 + tid] + red[768 + tid];
  part1[blockIdx.x * 256 + tid] = v;
}

// ---- parallel BN1 finish: 128 blocks (r21 proven, -100us class win) --------
__global__ __launch_bounds__(256) void k_stats_fin(
    const float* __restrict__ part1, const float* __restrict__ bn1_g,
    const float* __restrict__ bn1_b, float* __restrict__ stats1)
{
  __shared__ float red[256];
  const int c = blockIdx.x;
  const int t = threadIdx.x;
  float s = 0.f, q = 0.f;
#pragma unroll
  for (int i = t; i < NBLK_MAIN; i += 256){
    s += part1[(size_t)i * 256 + c];
    q += part1[(size_t)i * 256 + 128 + c];
  }
  red[t] = s; __syncthreads();
  for (int o = 128; o > 0; o >>= 1){ if (t < o) red[t] += red[t + o]; __syncthreads(); }
  float sumv = red[0]; __syncthreads();
  red[t] = q; __syncthreads();
  for (int o = 128; o > 0; o >>= 1){ if (t < o) red[t] += red[t + o]; __syncthreads(); }
  if (t == 0){
    const float inv = 1.f / (float)(N_ATOMS * M_NBR);
    float mu = sumv * inv;
    float var = red[0] * inv - mu * mu;
    float sc = bn1_g[c] * rsqrtf(var + EPSV);
    stats1[c] = sc;
    stats1[128 + c] = bn1_b[c] - mu * sc;
  }
}

// ---------------- K4a (gated path): streaming BN1+gate+sum ------------------
__global__ __launch_bounds__(256) void k_reduce_g(
    const unsigned* __restrict__ gated, const float* __restrict__ stats1,
    float* __restrict__ nbr_sumed, float* __restrict__ part2)
{
  __shared__ float red[512];
  const int tid = threadIdx.x, lane = tid & 63, w = tid >> 6;
  const float sc0 = stats1[lane],       sc1 = stats1[64 + lane];
  const float tc0 = stats1[128 + lane], tc1 = stats1[192 + lane];
  const int wg = blockIdx.x * 4 + w, nw = gridDim.x * 4;
  float bs = 0.f, bq = 0.f;
  for (int a = wg; a < N_ATOMS; a += nw){
    const size_t base = (size_t)a * M_NBR * 64 + lane;
    float acc = 0.f;
#pragma unroll
    for (int m = 0; m < M_NBR; ++m){
      unsigned gv = gated[base + m * 64];
      acc += sigmoidf(unlo(gv) * sc0 + tc0) * softplusf(unhi(gv) * sc1 + tc1);
    }
    nbr_sumed[(size_t)a * 64 + lane] = acc;
    bs += acc; bq += acc * acc;
  }
  red[w * 128 + lane]      = bs;
  red[w * 128 + 64 + lane] = bq;
  __syncthreads();
  if (tid < 128){
    float v = red[tid] + red[128 + tid] + red[256 + tid] + red[384 + tid];
    part2[blockIdx.x * 128 + tid] = v;
  }
}

// ---------------- K4b (fallback): recompute g, BN1, gate, sum ---------------
#define GBODYR(MM) { \
    const float* frow = nbr_fea + (size_t)(base + MM) * NBR_FEA; \
    float g0 = p10 + unlo(rw##MM); \
    float g1 = p11 + unhi(rw##MM); \
    _Pragma("unroll") \
    for (int k = 0; k < NBR_FEA; ++k){ \
      float aa = frow[k]; \
      g0 += aa * unlo(wbp[k]); \
      g1 += aa * unhi(wbp[k]); \
    } \
    acc += sigmoidf(g0 * sc0 + tc0) * softplusf(g1 * sc1 + tc1); }

__global__ __launch_bounds__(256) void k_reduce_r(
    const float* __restrict__ nbr_fea, const int* __restrict__ nbr_idx,
    const float* __restrict__ fc_w, const unsigned* __restrict__ proj1p,
    const unsigned* __restrict__ proj2p, const float* __restrict__ stats1,
    float* __restrict__ nbr_sumed, float* __restrict__ part2)
{
  __shared__ float red[512];
  const int tid = threadIdx.x, lane = tid & 63, w = tid >> 6;
  unsigned wbp[NBR_FEA];
#pragma unroll
  for (int k = 0; k < NBR_FEA; ++k){
    float w0 = fc_w[(128 + k) * 128 + lane];
    float w1 = fc_w[(128 + k) * 128 + 64 + lane];
    wbp[k] = pack2(w0, w1);
  }
  const float sc0 = stats1[lane],       sc1 = stats1[64 + lane];
  const float tc0 = stats1[128 + lane], tc1 = stats1[192 + lane];
  const int gw = blockIdx.x * 4 + w, nw = gridDim.x * 4;
  const int q = N_ATOMS / nw, rr = N_ATOMS % nw;
  const int a0 = gw * q + (gw < rr ? gw : rr);
  const int a1 = a0 + q + (gw < rr ? 1 : 0);
  float bs = 0.f, bq = 0.f;
  for (int a = a0; a < a1; ++a){
    const int au = __builtin_amdgcn_readfirstlane(a);
    const int base = au * M_NBR;
    const int* jrow = nbr_idx + base;
    unsigned p1v = proj1p[(size_t)au * 64 + lane];
    LOADRW(0) LOADRW(1) LOADRW(2) LOADRW(3) LOADRW(4) LOADRW(5)
    LOADRW(6) LOADRW(7) LOADRW(8) LOADRW(9) LOADRW(10) LOADRW(11)
    const float p10 = unlo(p1v), p11 = unhi(p1v);
    float acc = 0.f;
    GBODYR(0) GBODYR(1) GBODYR(2) GBODYR(3) GBODYR(4) GBODYR(5)
    GBODYR(6) GBODYR(7) GBODYR(8) GBODYR(9) GBODYR(10) GBODYR(11)
    nbr_sumed[(size_t)au * 64 + lane] = acc;
    bs += acc; bq += acc * acc;
  }
  red[w * 128 + lane]      = bs;
  red[w * 128 + 64 + lane] = bq;
  __syncthreads();
  if (tid < 128){
    float v = red[tid] + red[128 + tid] + red[256 + tid] + red[384 + tid];
    part2[blockIdx.x * 128 + tid] = v;
  }
}

// ---- parallel BN2 finish: 64 blocks (r21 proven) ---------------------------
__global__ __launch_bounds__(256) void k_red_fin(
    const float* __restrict__ part2, const float* __restrict__ bn2_g,
    const float* __restrict__ bn2_b, float* __restrict__ stats2)
{
  __shared__ float red[256];
  const int c = blockIdx.x;
  const int t = threadIdx.x;
  float s = 0.f, q = 0.f;
#pragma unroll
  for (int i = t; i < NBLK_MAIN; i += 256){
    s += part2[(size_t)i * 128 + c];
    q += part2[(size_t)i * 128 + 64 + c];
  }
  red[t] = s; __syncthreads();
  for (int o = 128; o > 0; o >>= 1){ if (t < o) red[t] += red[t + o]; __syncthreads(); }
  float sumv = red[0]; __syncthreads();
  red[t] = q; __syncthreads();
  for (int o = 128; o > 0; o >>= 1){ if (t < o) red[t] += red[t + o]; __syncthreads(); }
  if (t == 0){
    const float inv = 1.f / (float)N_ATOMS;
    float mu = sumv * inv;
    float var = red[0] * inv - mu * mu;
    float sc = bn2_g[c] * rsqrtf(var + EPSV);
    stats2[c] = sc;
    stats2[64 + c] = bn2_b[c] - mu * sc;
  }
}

// ---------------- K5: out = softplus(atom_tf + BN2(nbr_sumed)) --------------
__global__ __launch_bounds__(256) void k_final(
    const float* __restrict__ atom_tf, const float* __restrict__ ns,
    const float* __restrict__ stats2, float* __restrict__ out)
{
  int i = blockIdx.x * 256 + threadIdx.x;
  if (i >= N_ATOMS * 64) return;
  int c = i & 63;
  float x = atom_tf[i] + ns[i] * stats2[c] + stats2[64 + c];
  out[i] = softplusf(x);
}

extern "C" void kernel_launch(void* const* d_in, const int* in_sizes, int n_in,
                              void* d_out, int out_size, void* d_ws, size_t ws_size,
                              hipStream_t stream)
{
  const float* atom_in = (const float*)d_in[0];
  const float* nbr_fea = (const float*)d_in[1];
  const float* adj     = (const float*)d_in[2];
  const float* w1 = (const float*)d_in[3];
  const float* b1 = (const float*)d_in[4];
  const float* w2 = (const float*)d_in[5];
  const float* b2 = (const float*)d_in[6];
  const float* tln1_g = (const float*)d_in[7];
  const float* tln1_b = (const float*)d_in[8];
  const float* tln2_g = (const float*)d_in[9];
  const float* tln2_b = (const float*)d_in[10];
  const float* fc_w = (const float*)d_in[11];
  const float* fc_b = (const float*)d_in[12];
  const float* bn1_g = (const float*)d_in[13];
  const float* bn1_b = (const float*)d_in[14];
  const float* bn2_g = (const float*)d_in[15];
  const float* bn2_b = (const float*)d_in[16];
  const int* nbr_idx = (const int*)d_in[17];
  const int* cidx    = (const int*)d_in[18];
  float* out = (float*)d_out;

  char* ws = (char*)d_ws;
  size_t off = 0;
  float* atom_tf = (float*)(ws + off);    off += (size_t)N_ATOMS * 64 * 4;
  unsigned* proj1p = (unsigned*)(ws + off); off += (size_t)N_ATOMS * 64 * 4;
  unsigned* proj2p = (unsigned*)(ws + off); off += (size_t)N_ATOMS * 64 * 4;
  float* nbr_sumed = (float*)(ws + off);  off += (size_t)N_ATOMS * 64 * 4;
  float* part1 = (float*)(ws + off);      off += (size_t)NBLK_MAIN * 256 * 4;
  float* stats1 = (float*)(ws + off);     off += 256 * 4;
  float* part2 = (float*)(ws + off);      off += (size_t)NBLK_MAIN * 128 * 4;
  float* stats2 = (float*)(ws + off);     off += 128 * 4;
  unsigned* gated = (unsigned*)(ws + off);
  const size_t need_gated = off + (size_t)N_ATOMS * M_NBR * 64 * 4;
  const bool use_gated = (ws_size >= need_gated);

  // ln1 aliases nbr_sumed: consumed by k_ff, overwritten later by k_reduce_*.
  float* ln1 = nbr_sumed;

  k_attn<<<B_CRY, 512, 0, stream>>>(atom_in, adj, tln1_g, tln1_b, cidx, ln1);
  k_ff<<<2048, 256, 0, stream>>>(ln1, atom_in, cidx, w1, b1, w2, b2,
      tln2_g, tln2_b, fc_w, fc_b, atom_tf, proj1p, proj2p);
  if (use_gated){
    k_stats<1><<<NBLK_MAIN, 256, 0, stream>>>(nbr_fea, nbr_idx, fc_w, proj1p,
        proj2p, part1, gated);
    k_stats_fin<<<128, 256, 0, stream>>>(part1, bn1_g, bn1_b, stats1);
    k_reduce_g<<<NBLK_MAIN, 256, 0, stream>>>(gated, stats1, nbr_sumed, part2);
  } else {
    k_stats<0><<<NBLK_MAIN, 256, 0, stream>>>(nbr_fea, nbr_idx, fc_w, proj1p,
        proj2p, part1, gated);
    k_stats_fin<<<128, 256, 0, stream>>>(part1, bn1_g, bn1_b, stats1);
    k_reduce_r<<<NBLK_MAIN, 256, 0, stream>>>(nbr_fea, nbr_idx, fc_w, proj1p,
        proj2p, stats1, nbr_sumed, part2);
  }
  k_red_fin<<<64, 256, 0, stream>>>(part2, bn2_g, bn2_b, stats2);
  k_final<<<(N_ATOMS * 64 + 255) / 256, 256, 0, stream>>>(atom_tf, nbr_sumed, stats2, out);
}

// Round 23
// 339.814 us; speedup vs baseline: 1.5894x; 1.0044x over previous
//
#include <hip/hip_runtime.h>
#include <math.h>

#define N_ATOMS 60000
#define M_NBR   12
#define D_FEA   64
#define NBR_FEA 41
#define B_CRY   1200
#define NA_CRY  50
#define EPSV    1e-5f

#define NBLK_MAIN 2048   // blocks for k_stats (4 waves each)

typedef _Float16 h2 __attribute__((ext_vector_type(2)));
#define CVTPK(a, b) __builtin_bit_cast(h2, __builtin_amdgcn_cvt_pkrtz((a), (b)))

__device__ __forceinline__ float wsum(float v){
#pragma unroll
  for (int o = 32; o > 0; o >>= 1) v += __shfl_xor(v, o, 64);
  return v;
}
__device__ __forceinline__ float wmax64(float v){
#pragma unroll
  for (int o = 32; o > 0; o >>= 1) v = fmaxf(v, __shfl_xor(v, o, 64));
  return v;
}
__device__ __forceinline__ float softplusf(float x){
  return fmaxf(x, 0.f) + __logf(1.f + __expf(-fabsf(x)));
}
__device__ __forceinline__ float sigmoidf(float x){
  return 1.f / (1.f + __expf(-x));
}
// round-to-nearest-even fp32 -> bf16 bits (low 16)
__device__ __forceinline__ unsigned bf16_rne(float x){
  unsigned u = __float_as_uint(x);
  return (u + 0x7fffu + ((u >> 16) & 1u)) >> 16;
}
__device__ __forceinline__ unsigned pack2(float lo, float hi){
  return bf16_rne(lo) | (bf16_rne(hi) << 16);
}
__device__ __forceinline__ float unlo(unsigned u){ return __uint_as_float(u << 16); }
__device__ __forceinline__ float unhi(unsigned u){ return __uint_as_float(u & 0xffff0000u); }

// ---------------- K0: pre-pack bond weights as f16 k-pairs ------------------
// wpk[kk*128 + c] = (fc_w[128+2kk][c], fc_w[129+2kk][c]) as f16x2 (kk=20: hi=0)
// Pre-converting in MEMORY removes the r12 remat failure (in-kernel
// load+convert chains got re-executed every iteration).
__global__ __launch_bounds__(256) void k_prep(
    const float* __restrict__ fc_w, unsigned* __restrict__ wpk)
{
  int t = blockIdx.x * 256 + threadIdx.x;
  if (t >= 21 * 128) return;
  int kk = t >> 7, c = t & 127;
  float lo = fc_w[(128 + 2 * kk) * 128 + c];
  float hi = (kk < 20) ? fc_w[(129 + 2 * kk) * 128 + c] : 0.f;
  wpk[t] = __builtin_bit_cast(unsigned, __builtin_amdgcn_cvt_pkrtz(lo, hi));
}

// ---------------- K1a: attention half (phases 1-5) -> ln1 [N,64] ------------
__global__ __launch_bounds__(512, 4) void k_attn(
    const float* __restrict__ atom_in, const float* __restrict__ adj,
    const float* __restrict__ g1v, const float* __restrict__ be1,
    const int* __restrict__ cidx, float* __restrict__ ln1)
{
  __shared__ float s_a[NA_CRY * D_FEA];        // src rows
  __shared__ float s_b[D_FEA * (NA_CRY + 1)];  // srcT(stride 51) / x
  __shared__ float s_c[NA_CRY * D_FEA];        // scores

  const int tid  = threadIdx.x;
  const int b    = blockIdx.x;
  const int lane = tid & 63;
  const int w    = tid >> 6;   // 0..7

  for (int p = tid; p < NA_CRY * D_FEA; p += 512){
    int i = p >> 6, d = p & 63;
    int a = cidx[b * NA_CRY + i];
    float v = atom_in[(size_t)a * D_FEA + d];
    s_a[p] = v;
    s_b[d * (NA_CRY + 1) + i] = v;
  }
  __syncthreads();

  const float scale = 0.125f; // 1/sqrt(64)
  {
    const float* adjb = adj + (size_t)b * NA_CRY * NA_CRY;
    for (int t = tid; t < 625; t += 512){
      int i0 = (t / 25) * 2, j0 = (t % 25) * 2;
      float a00 = 0.f, a01 = 0.f, a10 = 0.f, a11 = 0.f;
#pragma unroll 8
      for (int d = 0; d < D_FEA; ++d){
        float va0 = s_a[i0 * D_FEA + d];
        float va1 = s_a[(i0 + 1) * D_FEA + d];
        float vb0 = s_b[d * (NA_CRY + 1) + j0];
        float vb1 = s_b[d * (NA_CRY + 1) + j0 + 1];
        a00 += va0 * vb0; a01 += va0 * vb1;
        a10 += va1 * vb0; a11 += va1 * vb1;
      }
      s_c[i0 * NA_CRY + j0]           = a00 * scale * adjb[i0 * NA_CRY + j0];
      s_c[i0 * NA_CRY + j0 + 1]       = a01 * scale * adjb[i0 * NA_CRY + j0 + 1];
      s_c[(i0 + 1) * NA_CRY + j0]     = a10 * scale * adjb[(i0 + 1) * NA_CRY + j0];
      s_c[(i0 + 1) * NA_CRY + j0 + 1] = a11 * scale * adjb[(i0 + 1) * NA_CRY + j0 + 1];
    }
  }
  __syncthreads();

  for (int r = w; r < NA_CRY; r += 8){
    float v = (lane < NA_CRY) ? s_c[r * NA_CRY + lane] : -1e30f;
    float mx = wmax64(v);
    float e = (lane < NA_CRY) ? __expf(v - mx) : 0.f;
    float s = wsum(e);
    if (lane < NA_CRY) s_c[r * NA_CRY + lane] = e / s;
  }
  __syncthreads();

  for (int t = tid; t < 25 * D_FEA; t += 512){
    int nh = t >> 6, d = t & 63;
    int n0 = nh * 2, n1 = n0 + 1;
    float x0 = 0.f, x1 = 0.f;
#pragma unroll 10
    for (int m = 0; m < NA_CRY; ++m){
      float sa = s_a[m * D_FEA + d];
      x0 += s_c[n0 * NA_CRY + m] * sa;
      x1 += s_c[n1 * NA_CRY + m] * sa;
    }
    s_b[n0 * D_FEA + d] = s_a[n0 * D_FEA + d] + x0;
    s_b[n1 * D_FEA + d] = s_a[n1 * D_FEA + d] + x1;
  }
  __syncthreads();

  for (int r = w; r < NA_CRY; r += 8){
    float x = s_b[r * D_FEA + lane];
    float mu = wsum(x) * (1.f / 64.f);
    float dx = x - mu;
    float var = wsum(dx * dx) * (1.f / 64.f);
    ln1[(size_t)(b * NA_CRY + r) * D_FEA + lane] =
        dx * rsqrtf(var + EPSV) * g1v[lane] + be1[lane];
  }
}

// ---------------- K1b: FF + LN2 + projections, barrier-free -----------------
__global__ __launch_bounds__(256) void k_ff(
    const float* __restrict__ ln1, const float* __restrict__ atom_in,
    const int* __restrict__ cidx,
    const float* __restrict__ w1, const float* __restrict__ b1,
    const float* __restrict__ w2, const float* __restrict__ b2,
    const float* __restrict__ g2v, const float* __restrict__ be2,
    const float* __restrict__ fc_w, const float* __restrict__ fc_b,
    float* __restrict__ atom_tf, unsigned* __restrict__ proj1p,
    unsigned* __restrict__ proj2p)
{
  __shared__ float sl[4][8][64];
  const int tid = threadIdx.x, lane = tid & 63, w = tid >> 6;
  float (*A)[64] = &sl[w][0];
  float (*Bs)[64] = &sl[w][4];

  const int gw = blockIdx.x * 4 + w, nw = gridDim.x * 4;
  const int NGRP = N_ATOMS / 4;
  for (int g = gw; g < NGRP; g += nw){
    const int r0 = g * 4;
    float ln0 = ln1[(size_t)(r0 + 0) * 64 + lane];
    float ln1v = ln1[(size_t)(r0 + 1) * 64 + lane];
    float ln2 = ln1[(size_t)(r0 + 2) * 64 + lane];
    float ln3 = ln1[(size_t)(r0 + 3) * 64 + lane];
    A[0][lane] = ln0; A[1][lane] = ln1v; A[2][lane] = ln2; A[3][lane] = ln3;
    __builtin_amdgcn_s_waitcnt(0);

    float h0a = 0.f, h1a = 0.f, h2a = 0.f, h3a = 0.f;
    float h0b = 0.f, h1b = 0.f, h2b = 0.f, h3b = 0.f;
#pragma unroll 8
    for (int k = 0; k < D_FEA; k += 2){
      float wv0 = w1[k * D_FEA + lane];
      float wv1 = w1[(k + 1) * D_FEA + lane];
      h0a += A[0][k] * wv0; h0b += A[0][k + 1] * wv1;
      h1a += A[1][k] * wv0; h1b += A[1][k + 1] * wv1;
      h2a += A[2][k] * wv0; h2b += A[2][k + 1] * wv1;
      h3a += A[3][k] * wv0; h3b += A[3][k + 1] * wv1;
    }
    float bb1 = b1[lane];
    float h0 = fmaxf(bb1 + h0a + h0b, 0.f);
    float h1 = fmaxf(bb1 + h1a + h1b, 0.f);
    float h2 = fmaxf(bb1 + h2a + h2b, 0.f);
    float h3 = fmaxf(bb1 + h3a + h3b, 0.f);
    Bs[0][lane] = h0; Bs[1][lane] = h1; Bs[2][lane] = h2; Bs[3][lane] = h3;
    __builtin_amdgcn_s_waitcnt(0);

    float t0a = 0.f, t1a = 0.f, t2a = 0.f, t3a = 0.f;
    float t0b = 0.f, t1b = 0.f, t2b = 0.f, t3b = 0.f;
#pragma unroll 8
    for (int k = 0; k < D_FEA; k += 2){
      float wv0 = w2[k * D_FEA + lane];
      float wv1 = w2[(k + 1) * D_FEA + lane];
      t0a += Bs[0][k] * wv0; t0b += Bs[0][k + 1] * wv1;
      t1a += Bs[1][k] * wv0; t1b += Bs[1][k + 1] * wv1;
      t2a += Bs[2][k] * wv0; t2b += Bs[2][k + 1] * wv1;
      t3a += Bs[3][k] * wv0; t3b += Bs[3][k + 1] * wv1;
    }
    float bb2 = b2[lane];
    float t0 = ln0 + bb2 + t0a + t0b;
    float t1 = ln1v + bb2 + t1a + t1b;
    float t2 = ln2 + bb2 + t2a + t2b;
    float t3 = ln3 + bb2 + t3a + t3b;

    float gv = g2v[lane], bv = be2[lane];
#define LN2ROW(TT, JJ) { \
      float mu = wsum(TT) * (1.f / 64.f); \
      float dx = (TT) - mu; \
      float var = wsum(dx * dx) * (1.f / 64.f); \
      float res = dx * rsqrtf(var + EPSV) * gv + bv; \
      atom_tf[(size_t)(r0 + JJ) * 64 + lane] = res; \
      A[JJ][lane] = res; }
    LN2ROW(t0, 0) LN2ROW(t1, 1) LN2ROW(t2, 2) LN2ROW(t3, 3)
#undef LN2ROW

    const int ga0 = cidx[r0], ga1 = cidx[r0 + 1], ga2 = cidx[r0 + 2], ga3 = cidx[r0 + 3];
    Bs[0][lane] = atom_in[(size_t)ga0 * 64 + lane];
    Bs[1][lane] = atom_in[(size_t)ga1 * 64 + lane];
    Bs[2][lane] = atom_in[(size_t)ga2 * 64 + lane];
    Bs[3][lane] = atom_in[(size_t)ga3 * 64 + lane];
    __builtin_amdgcn_s_waitcnt(0);

    const float bb0 = fc_b[lane], bb6 = fc_b[64 + lane];
    float A1 = bb0, A2 = bb6, A3 = 0.f, A4 = 0.f;
    float B1 = bb0, B2 = bb6, B3 = 0.f, B4 = 0.f;
    float C1 = bb0, C2 = bb6, C3 = 0.f, C4 = 0.f;
    float D1 = bb0, D2 = bb6, D3 = 0.f, D4 = 0.f;
#pragma unroll 4
    for (int k = 0; k < D_FEA; ++k){
      float w0 = fc_w[k * 128 + lane];
      float w6 = fc_w[k * 128 + 64 + lane];
      float v0 = fc_w[(64 + k) * 128 + lane];
      float v6 = fc_w[(64 + k) * 128 + 64 + lane];
      float ta = A[0][k], tb = A[1][k], tc = A[2][k], td = A[3][k];
      float sa = Bs[0][k], sb = Bs[1][k], sc = Bs[2][k], sd = Bs[3][k];
      A1 += ta * w0; A2 += ta * w6; A3 += sa * v0; A4 += sa * v6;
      B1 += tb * w0; B2 += tb * w6; B3 += sb * v0; B4 += sb * v6;
      C1 += tc * w0; C2 += tc * w6; C3 += sc * v0; C4 += sc * v6;
      D1 += td * w0; D2 += td * w6; D3 += sd * v0; D4 += sd * v6;
    }
    proj1p[(size_t)(r0 + 0) * 64 + lane] = pack2(A1, A2);
    proj1p[(size_t)(r0 + 1) * 64 + lane] = pack2(B1, B2);
    proj1p[(size_t)(r0 + 2) * 64 + lane] = pack2(C1, C2);
    proj1p[(size_t)(r0 + 3) * 64 + lane] = pack2(D1, D2);
    proj2p[(size_t)ga0 * 64 + lane] = pack2(A3, A4);
    proj2p[(size_t)ga1 * 64 + lane] = pack2(B3, B4);
    proj2p[(size_t)ga2 * 64 + lane] = pack2(C3, C4);
    proj2p[(size_t)ga3 * 64 + lane] = pack2(D3, D4);
  }
}

// ---------------- K3: BN1 stats + store pre-BN g (bf16x2) -------------------
// r22 diagnosis: VALU-bound (53% busy, 4 VALU/k: 2 unpack + 2 FMA). Inner
// loop now v_dot2_f32_f16: weights PRE-PACKED in ws by k_prep (plain u32
// loads of wf0[21]/wf1[21] mirror the remat-proof wbp pattern); per k-pair
// 1 cvt_pkrtz + 2 fdot2 = 1.5 VALU/k.
#define LOADRW(MM) unsigned rw##MM = proj2p[(size_t)__builtin_amdgcn_readfirstlane(jrow[MM]) * 64 + lane];

#define STAGE(AA, BUF) { \
    const float* srcp = nbr_fea + (size_t)(AA) * (M_NBR * NBR_FEA); \
    float* dstp = s_frow + (w * 2 + (BUF)) * 512; \
    __builtin_amdgcn_global_load_lds(srcp + lane * 4, dstp, 16, 0, 0); \
    if (lane < 59) \
      __builtin_amdgcn_global_load_lds(srcp + 256 + lane * 4, dstp + 256, 16, 0, 0); \
  }

#define GBODY(MM) { \
    float g0 = p10 + unlo(rw##MM); \
    float g1 = p11 + unhi(rw##MM); \
    const float* frm = fr + MM * NBR_FEA; \
    _Pragma("unroll") \
    for (int kk = 0; kk < 20; ++kk){ \
      h2 fa = CVTPK(frm[2 * kk], frm[2 * kk + 1]); \
      g0 = __builtin_amdgcn_fdot2(fa, __builtin_bit_cast(h2, wf0[kk]), g0, false); \
      g1 = __builtin_amdgcn_fdot2(fa, __builtin_bit_cast(h2, wf1[kk]), g1, false); \
    } \
    { h2 fa = CVTPK(frm[40], 0.f); \
      g0 = __builtin_amdgcn_fdot2(fa, __builtin_bit_cast(h2, wf0[20]), g0, false); \
      g1 = __builtin_amdgcn_fdot2(fa, __builtin_bit_cast(h2, wf1[20]), g1, false); } \
    if (STORE) gated[(size_t)(base + MM) * 64 + lane] = pack2(g0, g1); \
    s0 += g0; q0 += g0 * g0; \
    s1 += g1; q1 += g1 * g1; }

template<int STORE>
__global__ __launch_bounds__(256) void k_stats(
    const float* __restrict__ nbr_fea, const int* __restrict__ nbr_idx,
    const unsigned* __restrict__ wpk, const unsigned* __restrict__ proj1p,
    const unsigned* __restrict__ proj2p, float* __restrict__ part1,
    unsigned* __restrict__ gated)
{
  __shared__ float red[1024];
  __shared__ float s_frow[4 * 2 * 512];
  const int tid = threadIdx.x, lane = tid & 63, w = tid >> 6;

  unsigned wf0[21], wf1[21];
#pragma unroll
  for (int kk = 0; kk < 21; ++kk){
    wf0[kk] = wpk[kk * 128 + lane];
    wf1[kk] = wpk[kk * 128 + 64 + lane];
  }

  const int gw = blockIdx.x * 4 + w, nw = gridDim.x * 4;
  const int q = N_ATOMS / nw, rr = N_ATOMS % nw;
  const int a0 = gw * q + (gw < rr ? gw : rr);
  const int a1 = a0 + q + (gw < rr ? 1 : 0);
  float s0 = 0.f, s1 = 0.f, q0 = 0.f, q1 = 0.f;
  int cur = 0;
  if (a0 < a1){ STAGE(a0, 0); }
  for (int a = a0; a < a1; ++a){
    const int au = __builtin_amdgcn_readfirstlane(a);
    const int base = au * M_NBR;
    const int* jrow = nbr_idx + base;
    unsigned p1v = proj1p[(size_t)au * 64 + lane];
    LOADRW(0) LOADRW(1) LOADRW(2) LOADRW(3) LOADRW(4) LOADRW(5)
    LOADRW(6) LOADRW(7) LOADRW(8) LOADRW(9) LOADRW(10) LOADRW(11)
    const int anext = (a + 1 < a1) ? (a + 1) : a;
    STAGE(anext, cur ^ 1);
    asm volatile("s_waitcnt vmcnt(2)" ::: "memory");
    const float* fr = s_frow + (w * 2 + cur) * 512;
    const float p10 = unlo(p1v), p11 = unhi(p1v);
    GBODY(0) GBODY(1) GBODY(2) GBODY(3) GBODY(4) GBODY(5)
    GBODY(6) GBODY(7) GBODY(8) GBODY(9) GBODY(10) GBODY(11)
    cur ^= 1;
  }
  red[w * 256 + lane]        = s0;
  red[w * 256 + 64 + lane]   = s1;
  red[w * 256 + 128 + lane]  = q0;
  red[w * 256 + 192 + lane]  = q1;
  __syncthreads();
  float v = red[tid] + red[256 + tid] + red[512 + tid] + red[768 + tid];
  part1[blockIdx.x * 256 + tid] = v;
}

// ---- parallel BN1 finish: 128 blocks (r21 proven) --------------------------
__global__ __launch_bounds__(256) void k_stats_fin(
    const float* __restrict__ part1, const float* __restrict__ bn1_g,
    const float* __restrict__ bn1_b, float* __restrict__ stats1)
{
  __shared__ float red[256];
  const int c = blockIdx.x;
  const int t = threadIdx.x;
  float s = 0.f, q = 0.f;
#pragma unroll
  for (int i = t; i < NBLK_MAIN; i += 256){
    s += part1[(size_t)i * 256 + c];
    q += part1[(size_t)i * 256 + 128 + c];
  }
  red[t] = s; __syncthreads();
  for (int o = 128; o > 0; o >>= 1){ if (t < o) red[t] += red[t + o]; __syncthreads(); }
  float sumv = red[0]; __syncthreads();
  red[t] = q; __syncthreads();
  for (int o = 128; o > 0; o >>= 1){ if (t < o) red[t] += red[t + o]; __syncthreads(); }
  if (t == 0){
    const float inv = 1.f / (float)(N_ATOMS * M_NBR);
    float mu = sumv * inv;
    float var = red[0] * inv - mu * mu;
    float sc = bn1_g[c] * rsqrtf(var + EPSV);
    stats1[c] = sc;
    stats1[128 + c] = bn1_b[c] - mu * sc;
  }
}

// ---------------- K4a (gated path): streaming BN1+gate+sum ------------------
__global__ __launch_bounds__(256) void k_reduce_g(
    const unsigned* __restrict__ gated, const float* __restrict__ stats1,
    float* __restrict__ nbr_sumed, float* __restrict__ part2)
{
  __shared__ float red[512];
  const int tid = threadIdx.x, lane = tid & 63, w = tid >> 6;
  const float sc0 = stats1[lane],       sc1 = stats1[64 + lane];
  const float tc0 = stats1[128 + lane], tc1 = stats1[192 + lane];
  const int wg = blockIdx.x * 4 + w, nw = gridDim.x * 4;
  float bs = 0.f, bq = 0.f;
  for (int a = wg; a < N_ATOMS; a += nw){
    const size_t base = (size_t)a * M_NBR * 64 + lane;
    float acc = 0.f;
#pragma unroll
    for (int m = 0; m < M_NBR; ++m){
      unsigned gv = gated[base + m * 64];
      acc += sigmoidf(unlo(gv) * sc0 + tc0) * softplusf(unhi(gv) * sc1 + tc1);
    }
    nbr_sumed[(size_t)a * 64 + lane] = acc;
    bs += acc; bq += acc * acc;
  }
  red[w * 128 + lane]      = bs;
  red[w * 128 + 64 + lane] = bq;
  __syncthreads();
  if (tid < 128){
    float v = red[tid] + red[128 + tid] + red[256 + tid] + red[384 + tid];
    part2[blockIdx.x * 128 + tid] = v;
  }
}

// ---------------- K4b (fallback): recompute g, BN1, gate, sum ---------------
#define GBODYR(MM) { \
    const float* frow = nbr_fea + (size_t)(base + MM) * NBR_FEA; \
    float g0 = p10 + unlo(rw##MM); \
    float g1 = p11 + unhi(rw##MM); \
    _Pragma("unroll") \
    for (int k = 0; k < NBR_FEA; ++k){ \
      float aa = frow[k]; \
      g0 += aa * unlo(wbp[k]); \
      g1 += aa * unhi(wbp[k]); \
    } \
    acc += sigmoidf(g0 * sc0 + tc0) * softplusf(g1 * sc1 + tc1); }

__global__ __launch_bounds__(256) void k_reduce_r(
    const float* __restrict__ nbr_fea, const int* __restrict__ nbr_idx,
    const float* __restrict__ fc_w, const unsigned* __restrict__ proj1p,
    const unsigned* __restrict__ proj2p, const float* __restrict__ stats1,
    float* __restrict__ nbr_sumed, float* __restrict__ part2)
{
  __shared__ float red[512];
  const int tid = threadIdx.x, lane = tid & 63, w = tid >> 6;
  unsigned wbp[NBR_FEA];
#pragma unroll
  for (int k = 0; k < NBR_FEA; ++k){
    float w0 = fc_w[(128 + k) * 128 + lane];
    float w1 = fc_w[(128 + k) * 128 + 64 + lane];
    wbp[k] = pack2(w0, w1);
  }
  const float sc0 = stats1[lane],       sc1 = stats1[64 + lane];
  const float tc0 = stats1[128 + lane], tc1 = stats1[192 + lane];
  const int gw = blockIdx.x * 4 + w, nw = gridDim.x * 4;
  const int q = N_ATOMS / nw, rr = N_ATOMS % nw;
  const int a0 = gw * q + (gw < rr ? gw : rr);
  const int a1 = a0 + q + (gw < rr ? 1 : 0);
  float bs = 0.f, bq = 0.f;
  for (int a = a0; a < a1; ++a){
    const int au = __builtin_amdgcn_readfirstlane(a);
    const int base = au * M_NBR;
    const int* jrow = nbr_idx + base;
    unsigned p1v = proj1p[(size_t)au * 64 + lane];
    LOADRW(0) LOADRW(1) LOADRW(2) LOADRW(3) LOADRW(4) LOADRW(5)
    LOADRW(6) LOADRW(7) LOADRW(8) LOADRW(9) LOADRW(10) LOADRW(11)
    const float p10 = unlo(p1v), p11 = unhi(p1v);
    float acc = 0.f;
    GBODYR(0) GBODYR(1) GBODYR(2) GBODYR(3) GBODYR(4) GBODYR(5)
    GBODYR(6) GBODYR(7) GBODYR(8) GBODYR(9) GBODYR(10) GBODYR(11)
    nbr_sumed[(size_t)au * 64 + lane] = acc;
    bs += acc; bq += acc * acc;
  }
  red[w * 128 + lane]      = bs;
  red[w * 128 + 64 + lane] = bq;
  __syncthreads();
  if (tid < 128){
    float v = red[tid] + red[128 + tid] + red[256 + tid] + red[384 + tid];
    part2[blockIdx.x * 128 + tid] = v;
  }
}

// ---- parallel BN2 finish: 64 blocks (r21 proven) ---------------------------
__global__ __launch_bounds__(256) void k_red_fin(
    const float* __restrict__ part2, const float* __restrict__ bn2_g,
    const float* __restrict__ bn2_b, float* __restrict__ stats2)
{
  __shared__ float red[256];
  const int c = blockIdx.x;
  const int t = threadIdx.x;
  float s = 0.f, q = 0.f;
#pragma unroll
  for (int i = t; i < NBLK_MAIN; i += 256){
    s += part2[(size_t)i * 128 + c];
    q += part2[(size_t)i * 128 + 64 + c];
  }
  red[t] = s; __syncthreads();
  for (int o = 128; o > 0; o >>= 1){ if (t < o) red[t] += red[t + o]; __syncthreads(); }
  float sumv = red[0]; __syncthreads();
  red[t] = q; __syncthreads();
  for (int o = 128; o > 0; o >>= 1){ if (t < o) red[t] += red[t + o]; __syncthreads(); }
  if (t == 0){
    const float inv = 1.f / (float)N_ATOMS;
    float mu = sumv * inv;
    float var = red[0] * inv - mu * mu;
    float sc = bn2_g[c] * rsqrtf(var + EPSV);
    stats2[c] = sc;
    stats2[64 + c] = bn2_b[c] - mu * sc;
  }
}

// ---------------- K5: out = softplus(atom_tf + BN2(nbr_sumed)) --------------
__global__ __launch_bounds__(256) void k_final(
    const float* __restrict__ atom_tf, const float* __restrict__ ns,
    const float* __restrict__ stats2, float* __restrict__ out)
{
  int i = blockIdx.x * 256 + threadIdx.x;
  if (i >= N_ATOMS * 64) return;
  int c = i & 63;
  float x = atom_tf[i] + ns[i] * stats2[c] + stats2[64 + c];
  out[i] = softplusf(x);
}

extern "C" void kernel_launch(void* const* d_in, const int* in_sizes, int n_in,
                              void* d_out, int out_size, void* d_ws, size_t ws_size,
                              hipStream_t stream)
{
  const float* atom_in = (const float*)d_in[0];
  const float* nbr_fea = (const float*)d_in[1];
  const float* adj     = (const float*)d_in[2];
  const float* w1 = (const float*)d_in[3];
  const float* b1 = (const float*)d_in[4];
  const float* w2 = (const float*)d_in[5];
  const float* b2 = (const float*)d_in[6];
  const float* tln1_g = (const float*)d_in[7];
  const float* tln1_b = (const float*)d_in[8];
  const float* tln2_g = (const float*)d_in[9];
  const float* tln2_b = (const float*)d_in[10];
  const float* fc_w = (const float*)d_in[11];
  const float* fc_b = (const float*)d_in[12];
  const float* bn1_g = (const float*)d_in[13];
  const float* bn1_b = (const float*)d_in[14];
  const float* bn2_g = (const float*)d_in[15];
  const float* bn2_b = (const float*)d_in[16];
  const int* nbr_idx = (const int*)d_in[17];
  const int* cidx    = (const int*)d_in[18];
  float* out = (float*)d_out;

  char* ws = (char*)d_ws;
  size_t off = 0;
  float* atom_tf = (float*)(ws + off);    off += (size_t)N_ATOMS * 64 * 4;
  unsigned* proj1p = (unsigned*)(ws + off); off += (size_t)N_ATOMS * 64 * 4;
  unsigned* proj2p = (unsigned*)(ws + off); off += (size_t)N_ATOMS * 64 * 4;
  float* nbr_sumed = (float*)(ws + off);  off += (size_t)N_ATOMS * 64 * 4;
  float* part1 = (float*)(ws + off);      off += (size_t)NBLK_MAIN * 256 * 4;
  float* stats1 = (float*)(ws + off);     off += 256 * 4;
  float* part2 = (float*)(ws + off);      off += (size_t)NBLK_MAIN * 128 * 4;
  float* stats2 = (float*)(ws + off);     off += 128 * 4;
  unsigned* wpk = (unsigned*)(ws + off);  off += 21 * 128 * 4;
  unsigned* gated = (unsigned*)(ws + off);
  const size_t need_gated = off + (size_t)N_ATOMS * M_NBR * 64 * 4;
  const bool use_gated = (ws_size >= need_gated);

  // ln1 aliases nbr_sumed: consumed by k_ff, overwritten later by k_reduce_*.
  float* ln1 = nbr_sumed;

  k_prep<<<11, 256, 0, stream>>>(fc_w, wpk);
  k_attn<<<B_CRY, 512, 0, stream>>>(atom_in, adj, tln1_g, tln1_b, cidx, ln1);
  k_ff<<<2048, 256, 0, stream>>>(ln1, atom_in, cidx, w1, b1, w2, b2,
      tln2_g, tln2_b, fc_w, fc_b, atom_tf, proj1p, proj2p);
  if (use_gated){
    k_stats<1><<<NBLK_MAIN, 256, 0, stream>>>(nbr_fea, nbr_idx, wpk, proj1p,
        proj2p, part1, gated);
    k_stats_fin<<<128, 256, 0, stream>>>(part1, bn1_g, bn1_b, stats1);
    k_reduce_g<<<NBLK_MAIN, 256, 0, stream>>>(gated, stats1, nbr_sumed, part2);
  } else {
    k_stats<0><<<NBLK_MAIN, 256, 0, stream>>>(nbr_fea, nbr_idx, wpk, proj1p,
        proj2p, part1, gated);
    k_stats_fin<<<128, 256, 0, stream>>>(part1, bn1_g, bn1_b, stats1);
    k_reduce_r<<<NBLK_MAIN, 256, 0, stream>>>(nbr_fea, nbr_idx, fc_w, proj1p,
        proj2p, stats1, nbr_sumed, part2);
  }
  k_red_fin<<<64, 256, 0, stream>>>(part2, bn2_g, bn2_b, stats2);
  k_final<<<(N_ATOMS * 64 + 255) / 256, 256, 0, stream>>>(atom_tf, nbr_sumed, stats2, out);
}

// Round 24
// 336.740 us; speedup vs baseline: 1.6039x; 1.0091x over previous
//
#include <hip/hip_runtime.h>
#include <math.h>

#define N_ATOMS 60000
#define M_NBR   12
#define D_FEA   64
#define NBR_FEA 41
#define B_CRY   1200
#define NA_CRY  50
#define EPSV    1e-5f

#define NBLK_MAIN 2048   // blocks for k_stats (4 waves each)

typedef _Float16 h2 __attribute__((ext_vector_type(2)));
#define CVTPK(a, b) __builtin_bit_cast(h2, __builtin_amdgcn_cvt_pkrtz((a), (b)))

__device__ __forceinline__ float wsum(float v){
#pragma unroll
  for (int o = 32; o > 0; o >>= 1) v += __shfl_xor(v, o, 64);
  return v;
}
__device__ __forceinline__ float wmax64(float v){
#pragma unroll
  for (int o = 32; o > 0; o >>= 1) v = fmaxf(v, __shfl_xor(v, o, 64));
  return v;
}
__device__ __forceinline__ float softplusf(float x){
  return fmaxf(x, 0.f) + __logf(1.f + __expf(-fabsf(x)));
}
__device__ __forceinline__ float sigmoidf(float x){
  return 1.f / (1.f + __expf(-x));
}
// round-to-nearest-even fp32 -> bf16 bits (low 16)
__device__ __forceinline__ unsigned bf16_rne(float x){
  unsigned u = __float_as_uint(x);
  return (u + 0x7fffu + ((u >> 16) & 1u)) >> 16;
}
__device__ __forceinline__ unsigned pack2(float lo, float hi){
  return bf16_rne(lo) | (bf16_rne(hi) << 16);
}
__device__ __forceinline__ float unlo(unsigned u){ return __uint_as_float(u << 16); }
__device__ __forceinline__ float unhi(unsigned u){ return __uint_as_float(u & 0xffff0000u); }

// ---------------- K0: pre-pack bond weights as f16 k-pairs (r23 proven) -----
__global__ __launch_bounds__(256) void k_prep(
    const float* __restrict__ fc_w, unsigned* __restrict__ wpk)
{
  int t = blockIdx.x * 256 + threadIdx.x;
  if (t >= 21 * 128) return;
  int kk = t >> 7, c = t & 127;
  float lo = fc_w[(128 + 2 * kk) * 128 + c];
  float hi = (kk < 20) ? fc_w[(129 + 2 * kk) * 128 + c] : 0.f;
  wpk[t] = __builtin_bit_cast(unsigned, __builtin_amdgcn_cvt_pkrtz(lo, hi));
}

// ---------------- K1a: attention half (phases 1-5) -> ln1 [N,64] ------------
__global__ __launch_bounds__(512, 4) void k_attn(
    const float* __restrict__ atom_in, const float* __restrict__ adj,
    const float* __restrict__ g1v, const float* __restrict__ be1,
    const int* __restrict__ cidx, float* __restrict__ ln1)
{
  __shared__ float s_a[NA_CRY * D_FEA];        // src rows
  __shared__ float s_b[D_FEA * (NA_CRY + 1)];  // srcT(stride 51) / x
  __shared__ float s_c[NA_CRY * D_FEA];        // scores

  const int tid  = threadIdx.x;
  const int b    = blockIdx.x;
  const int lane = tid & 63;
  const int w    = tid >> 6;   // 0..7

  for (int p = tid; p < NA_CRY * D_FEA; p += 512){
    int i = p >> 6, d = p & 63;
    int a = cidx[b * NA_CRY + i];
    float v = atom_in[(size_t)a * D_FEA + d];
    s_a[p] = v;
    s_b[d * (NA_CRY + 1) + i] = v;
  }
  __syncthreads();

  const float scale = 0.125f; // 1/sqrt(64)
  {
    const float* adjb = adj + (size_t)b * NA_CRY * NA_CRY;
    for (int t = tid; t < 625; t += 512){
      int i0 = (t / 25) * 2, j0 = (t % 25) * 2;
      float a00 = 0.f, a01 = 0.f, a10 = 0.f, a11 = 0.f;
#pragma unroll 8
      for (int d = 0; d < D_FEA; ++d){
        float va0 = s_a[i0 * D_FEA + d];
        float va1 = s_a[(i0 + 1) * D_FEA + d];
        float vb0 = s_b[d * (NA_CRY + 1) + j0];
        float vb1 = s_b[d * (NA_CRY + 1) + j0 + 1];
        a00 += va0 * vb0; a01 += va0 * vb1;
        a10 += va1 * vb0; a11 += va1 * vb1;
      }
      s_c[i0 * NA_CRY + j0]           = a00 * scale * adjb[i0 * NA_CRY + j0];
      s_c[i0 * NA_CRY + j0 + 1]       = a01 * scale * adjb[i0 * NA_CRY + j0 + 1];
      s_c[(i0 + 1) * NA_CRY + j0]     = a10 * scale * adjb[(i0 + 1) * NA_CRY + j0];
      s_c[(i0 + 1) * NA_CRY + j0 + 1] = a11 * scale * adjb[(i0 + 1) * NA_CRY + j0 + 1];
    }
  }
  __syncthreads();

  for (int r = w; r < NA_CRY; r += 8){
    float v = (lane < NA_CRY) ? s_c[r * NA_CRY + lane] : -1e30f;
    float mx = wmax64(v);
    float e = (lane < NA_CRY) ? __expf(v - mx) : 0.f;
    float s = wsum(e);
    if (lane < NA_CRY) s_c[r * NA_CRY + lane] = e / s;
  }
  __syncthreads();

  for (int t = tid; t < 25 * D_FEA; t += 512){
    int nh = t >> 6, d = t & 63;
    int n0 = nh * 2, n1 = n0 + 1;
    float x0 = 0.f, x1 = 0.f;
#pragma unroll 10
    for (int m = 0; m < NA_CRY; ++m){
      float sa = s_a[m * D_FEA + d];
      x0 += s_c[n0 * NA_CRY + m] * sa;
      x1 += s_c[n1 * NA_CRY + m] * sa;
    }
    s_b[n0 * D_FEA + d] = s_a[n0 * D_FEA + d] + x0;
    s_b[n1 * D_FEA + d] = s_a[n1 * D_FEA + d] + x1;
  }
  __syncthreads();

  for (int r = w; r < NA_CRY; r += 8){
    float x = s_b[r * D_FEA + lane];
    float mu = wsum(x) * (1.f / 64.f);
    float dx = x - mu;
    float var = wsum(dx * dx) * (1.f / 64.f);
    ln1[(size_t)(b * NA_CRY + r) * D_FEA + lane] =
        dx * rsqrtf(var + EPSV) * g1v[lane] + be1[lane];
  }
}

// ---------------- K1b: FF + LN2 + projections, barrier-free -----------------
__global__ __launch_bounds__(256) void k_ff(
    const float* __restrict__ ln1, const float* __restrict__ atom_in,
    const int* __restrict__ cidx,
    const float* __restrict__ w1, const float* __restrict__ b1,
    const float* __restrict__ w2, const float* __restrict__ b2,
    const float* __restrict__ g2v, const float* __restrict__ be2,
    const float* __restrict__ fc_w, const float* __restrict__ fc_b,
    float* __restrict__ atom_tf, unsigned* __restrict__ proj1p,
    unsigned* __restrict__ proj2p)
{
  __shared__ float sl[4][8][64];
  const int tid = threadIdx.x, lane = tid & 63, w = tid >> 6;
  float (*A)[64] = &sl[w][0];
  float (*Bs)[64] = &sl[w][4];

  const int gw = blockIdx.x * 4 + w, nw = gridDim.x * 4;
  const int NGRP = N_ATOMS / 4;
  for (int g = gw; g < NGRP; g += nw){
    const int r0 = g * 4;
    float ln0 = ln1[(size_t)(r0 + 0) * 64 + lane];
    float ln1v = ln1[(size_t)(r0 + 1) * 64 + lane];
    float ln2 = ln1[(size_t)(r0 + 2) * 64 + lane];
    float ln3 = ln1[(size_t)(r0 + 3) * 64 + lane];
    A[0][lane] = ln0; A[1][lane] = ln1v; A[2][lane] = ln2; A[3][lane] = ln3;
    __builtin_amdgcn_s_waitcnt(0);

    float h0a = 0.f, h1a = 0.f, h2a = 0.f, h3a = 0.f;
    float h0b = 0.f, h1b = 0.f, h2b = 0.f, h3b = 0.f;
#pragma unroll 8
    for (int k = 0; k < D_FEA; k += 2){
      float wv0 = w1[k * D_FEA + lane];
      float wv1 = w1[(k + 1) * D_FEA + lane];
      h0a += A[0][k] * wv0; h0b += A[0][k + 1] * wv1;
      h1a += A[1][k] * wv0; h1b += A[1][k + 1] * wv1;
      h2a += A[2][k] * wv0; h2b += A[2][k + 1] * wv1;
      h3a += A[3][k] * wv0; h3b += A[3][k + 1] * wv1;
    }
    float bb1 = b1[lane];
    float h0 = fmaxf(bb1 + h0a + h0b, 0.f);
    float h1 = fmaxf(bb1 + h1a + h1b, 0.f);
    float h2 = fmaxf(bb1 + h2a + h2b, 0.f);
    float h3 = fmaxf(bb1 + h3a + h3b, 0.f);
    Bs[0][lane] = h0; Bs[1][lane] = h1; Bs[2][lane] = h2; Bs[3][lane] = h3;
    __builtin_amdgcn_s_waitcnt(0);

    float t0a = 0.f, t1a = 0.f, t2a = 0.f, t3a = 0.f;
    float t0b = 0.f, t1b = 0.f, t2b = 0.f, t3b = 0.f;
#pragma unroll 8
    for (int k = 0; k < D_FEA; k += 2){
      float wv0 = w2[k * D_FEA + lane];
      float wv1 = w2[(k + 1) * D_FEA + lane];
      t0a += Bs[0][k] * wv0; t0b += Bs[0][k + 1] * wv1;
      t1a += Bs[1][k] * wv0; t1b += Bs[1][k + 1] * wv1;
      t2a += Bs[2][k] * wv0; t2b += Bs[2][k + 1] * wv1;
      t3a += Bs[3][k] * wv0; t3b += Bs[3][k + 1] * wv1;
    }
    float bb2 = b2[lane];
    float t0 = ln0 + bb2 + t0a + t0b;
    float t1 = ln1v + bb2 + t1a + t1b;
    float t2 = ln2 + bb2 + t2a + t2b;
    float t3 = ln3 + bb2 + t3a + t3b;

    float gv = g2v[lane], bv = be2[lane];
#define LN2ROW(TT, JJ) { \
      float mu = wsum(TT) * (1.f / 64.f); \
      float dx = (TT) - mu; \
      float var = wsum(dx * dx) * (1.f / 64.f); \
      float res = dx * rsqrtf(var + EPSV) * gv + bv; \
      atom_tf[(size_t)(r0 + JJ) * 64 + lane] = res; \
      A[JJ][lane] = res; }
    LN2ROW(t0, 0) LN2ROW(t1, 1) LN2ROW(t2, 2) LN2ROW(t3, 3)
#undef LN2ROW

    const int ga0 = cidx[r0], ga1 = cidx[r0 + 1], ga2 = cidx[r0 + 2], ga3 = cidx[r0 + 3];
    Bs[0][lane] = atom_in[(size_t)ga0 * 64 + lane];
    Bs[1][lane] = atom_in[(size_t)ga1 * 64 + lane];
    Bs[2][lane] = atom_in[(size_t)ga2 * 64 + lane];
    Bs[3][lane] = atom_in[(size_t)ga3 * 64 + lane];
    __builtin_amdgcn_s_waitcnt(0);

    const float bb0 = fc_b[lane], bb6 = fc_b[64 + lane];
    float A1 = bb0, A2 = bb6, A3 = 0.f, A4 = 0.f;
    float B1 = bb0, B2 = bb6, B3 = 0.f, B4 = 0.f;
    float C1 = bb0, C2 = bb6, C3 = 0.f, C4 = 0.f;
    float D1 = bb0, D2 = bb6, D3 = 0.f, D4 = 0.f;
#pragma unroll 4
    for (int k = 0; k < D_FEA; ++k){
      float w0 = fc_w[k * 128 + lane];
      float w6 = fc_w[k * 128 + 64 + lane];
      float v0 = fc_w[(64 + k) * 128 + lane];
      float v6 = fc_w[(64 + k) * 128 + 64 + lane];
      float ta = A[0][k], tb = A[1][k], tc = A[2][k], td = A[3][k];
      float sa = Bs[0][k], sb = Bs[1][k], sc = Bs[2][k], sd = Bs[3][k];
      A1 += ta * w0; A2 += ta * w6; A3 += sa * v0; A4 += sa * v6;
      B1 += tb * w0; B2 += tb * w6; B3 += sb * v0; B4 += sb * v6;
      C1 += tc * w0; C2 += tc * w6; C3 += sc * v0; C4 += sc * v6;
      D1 += td * w0; D2 += td * w6; D3 += sd * v0; D4 += sd * v6;
    }
    proj1p[(size_t)(r0 + 0) * 64 + lane] = pack2(A1, A2);
    proj1p[(size_t)(r0 + 1) * 64 + lane] = pack2(B1, B2);
    proj1p[(size_t)(r0 + 2) * 64 + lane] = pack2(C1, C2);
    proj1p[(size_t)(r0 + 3) * 64 + lane] = pack2(D1, D2);
    proj2p[(size_t)ga0 * 64 + lane] = pack2(A3, A4);
    proj2p[(size_t)ga1 * 64 + lane] = pack2(B3, B4);
    proj2p[(size_t)ga2 * 64 + lane] = pack2(C3, C4);
    proj2p[(size_t)ga3 * 64 + lane] = pack2(D3, D4);
  }
}

// ---------------- K3: BN1 stats + store pre-BN g (bf16x2) -------------------
// r23: dot2 inner loop (VALU 65%). r24 LDS diet: the 4KB red[] buffer pushed
// LDS to 20480B = exactly 8x160KiB -> runtime reserve may fit only 7
// blocks/CU (serial tail). Reduction now ALIASES s_frow (16KB total) after
// a vmcnt(0) drain (pending dummy-stage DMA would corrupt it otherwise).
#define LOADRW(MM) unsigned rw##MM = proj2p[(size_t)__builtin_amdgcn_readfirstlane(jrow[MM]) * 64 + lane];

#define STAGE(AA, BUF) { \
    const float* srcp = nbr_fea + (size_t)(AA) * (M_NBR * NBR_FEA); \
    float* dstp = s_frow + (w * 2 + (BUF)) * 512; \
    __builtin_amdgcn_global_load_lds(srcp + lane * 4, dstp, 16, 0, 0); \
    if (lane < 59) \
      __builtin_amdgcn_global_load_lds(srcp + 256 + lane * 4, dstp + 256, 16, 0, 0); \
  }

#define GBODY(MM) { \
    float g0 = p10 + unlo(rw##MM); \
    float g1 = p11 + unhi(rw##MM); \
    const float* frm = fr + MM * NBR_FEA; \
    _Pragma("unroll") \
    for (int kk = 0; kk < 20; ++kk){ \
      h2 fa = CVTPK(frm[2 * kk], frm[2 * kk + 1]); \
      g0 = __builtin_amdgcn_fdot2(fa, __builtin_bit_cast(h2, wf0[kk]), g0, false); \
      g1 = __builtin_amdgcn_fdot2(fa, __builtin_bit_cast(h2, wf1[kk]), g1, false); \
    } \
    { h2 fa = CVTPK(frm[40], 0.f); \
      g0 = __builtin_amdgcn_fdot2(fa, __builtin_bit_cast(h2, wf0[20]), g0, false); \
      g1 = __builtin_amdgcn_fdot2(fa, __builtin_bit_cast(h2, wf1[20]), g1, false); } \
    if (STORE) gated[(size_t)(base + MM) * 64 + lane] = pack2(g0, g1); \
    s0 += g0; q0 += g0 * g0; \
    s1 += g1; q1 += g1 * g1; }

template<int STORE>
__global__ __launch_bounds__(256) void k_stats(
    const float* __restrict__ nbr_fea, const int* __restrict__ nbr_idx,
    const unsigned* __restrict__ wpk, const unsigned* __restrict__ proj1p,
    const unsigned* __restrict__ proj2p, float* __restrict__ part1,
    unsigned* __restrict__ gated)
{
  __shared__ float s_frow[4 * 2 * 512];  // staging; reduction aliases after drain
  const int tid = threadIdx.x, lane = tid & 63, w = tid >> 6;

  unsigned wf0[21], wf1[21];
#pragma unroll
  for (int kk = 0; kk < 21; ++kk){
    wf0[kk] = wpk[kk * 128 + lane];
    wf1[kk] = wpk[kk * 128 + 64 + lane];
  }

  const int gw = blockIdx.x * 4 + w, nw = gridDim.x * 4;
  const int q = N_ATOMS / nw, rr = N_ATOMS % nw;
  const int a0 = gw * q + (gw < rr ? gw : rr);
  const int a1 = a0 + q + (gw < rr ? 1 : 0);
  float s0 = 0.f, s1 = 0.f, q0 = 0.f, q1 = 0.f;
  int cur = 0;
  if (a0 < a1){ STAGE(a0, 0); }
  for (int a = a0; a < a1; ++a){
    const int au = __builtin_amdgcn_readfirstlane(a);
    const int base = au * M_NBR;
    const int* jrow = nbr_idx + base;
    unsigned p1v = proj1p[(size_t)au * 64 + lane];
    LOADRW(0) LOADRW(1) LOADRW(2) LOADRW(3) LOADRW(4) LOADRW(5)
    LOADRW(6) LOADRW(7) LOADRW(8) LOADRW(9) LOADRW(10) LOADRW(11)
    const int anext = (a + 1 < a1) ? (a + 1) : a;
    STAGE(anext, cur ^ 1);
    asm volatile("s_waitcnt vmcnt(2)" ::: "memory");
    const float* fr = s_frow + (w * 2 + cur) * 512;
    const float p10 = unlo(p1v), p11 = unhi(p1v);
    GBODY(0) GBODY(1) GBODY(2) GBODY(3) GBODY(4) GBODY(5)
    GBODY(6) GBODY(7) GBODY(8) GBODY(9) GBODY(10) GBODY(11)
    cur ^= 1;
  }
  // drain ALL pending global_load_lds (dummy stage included) before aliasing
  asm volatile("s_waitcnt vmcnt(0)" ::: "memory");
  __syncthreads();
  float* red = s_frow;                 // alias: 1024 floats needed
  red[w * 256 + lane]        = s0;
  red[w * 256 + 64 + lane]   = s1;
  red[w * 256 + 128 + lane]  = q0;
  red[w * 256 + 192 + lane]  = q1;
  __syncthreads();
  float v = red[tid] + red[256 + tid] + red[512 + tid] + red[768 + tid];
  part1[blockIdx.x * 256 + tid] = v;
}

// ---- parallel BN1 finish: 128 blocks (r21 proven) --------------------------
__global__ __launch_bounds__(256) void k_stats_fin(
    const float* __restrict__ part1, const float* __restrict__ bn1_g,
    const float* __restrict__ bn1_b, float* __restrict__ stats1)
{
  __shared__ float red[256];
  const int c = blockIdx.x;
  const int t = threadIdx.x;
  float s = 0.f, q = 0.f;
#pragma unroll
  for (int i = t; i < NBLK_MAIN; i += 256){
    s += part1[(size_t)i * 256 + c];
    q += part1[(size_t)i * 256 + 128 + c];
  }
  red[t] = s; __syncthreads();
  for (int o = 128; o > 0; o >>= 1){ if (t < o) red[t] += red[t + o]; __syncthreads(); }
  float sumv = red[0]; __syncthreads();
  red[t] = q; __syncthreads();
  for (int o = 128; o > 0; o >>= 1){ if (t < o) red[t] += red[t + o]; __syncthreads(); }
  if (t == 0){
    const float inv = 1.f / (float)(N_ATOMS * M_NBR);
    float mu = sumv * inv;
    float var = red[0] * inv - mu * mu;
    float sc = bn1_g[c] * rsqrtf(var + EPSV);
    stats1[c] = sc;
    stats1[128 + c] = bn1_b[c] - mu * sc;
  }
}

// ---------------- K4a (gated path): streaming BN1+gate+sum ------------------
__global__ __launch_bounds__(256) void k_reduce_g(
    const unsigned* __restrict__ gated, const float* __restrict__ stats1,
    float* __restrict__ nbr_sumed, float* __restrict__ part2)
{
  __shared__ float red[512];
  const int tid = threadIdx.x, lane = tid & 63, w = tid >> 6;
  const float sc0 = stats1[lane],       sc1 = stats1[64 + lane];
  const float tc0 = stats1[128 + lane], tc1 = stats1[192 + lane];
  const int wg = blockIdx.x * 4 + w, nw = gridDim.x * 4;
  float bs = 0.f, bq = 0.f;
  for (int a = wg; a < N_ATOMS; a += nw){
    const size_t base = (size_t)a * M_NBR * 64 + lane;
    float acc = 0.f;
#pragma unroll
    for (int m = 0; m < M_NBR; ++m){
      unsigned gv = gated[base + m * 64];
      acc += sigmoidf(unlo(gv) * sc0 + tc0) * softplusf(unhi(gv) * sc1 + tc1);
    }
    nbr_sumed[(size_t)a * 64 + lane] = acc;
    bs += acc; bq += acc * acc;
  }
  red[w * 128 + lane]      = bs;
  red[w * 128 + 64 + lane] = bq;
  __syncthreads();
  if (tid < 128){
    float v = red[tid] + red[128 + tid] + red[256 + tid] + red[384 + tid];
    part2[blockIdx.x * 128 + tid] = v;
  }
}

// ---------------- K4b (fallback): recompute g, BN1, gate, sum ---------------
#define GBODYR(MM) { \
    const float* frow = nbr_fea + (size_t)(base + MM) * NBR_FEA; \
    float g0 = p10 + unlo(rw##MM); \
    float g1 = p11 + unhi(rw##MM); \
    _Pragma("unroll") \
    for (int k = 0; k < NBR_FEA; ++k){ \
      float aa = frow[k]; \
      g0 += aa * unlo(wbp[k]); \
      g1 += aa * unhi(wbp[k]); \
    } \
    acc += sigmoidf(g0 * sc0 + tc0) * softplusf(g1 * sc1 + tc1); }

__global__ __launch_bounds__(256) void k_reduce_r(
    const float* __restrict__ nbr_fea, const int* __restrict__ nbr_idx,
    const float* __restrict__ fc_w, const unsigned* __restrict__ proj1p,
    const unsigned* __restrict__ proj2p, const float* __restrict__ stats1,
    float* __restrict__ nbr_sumed, float* __restrict__ part2)
{
  __shared__ float red[512];
  const int tid = threadIdx.x, lane = tid & 63, w = tid >> 6;
  unsigned wbp[NBR_FEA];
#pragma unroll
  for (int k = 0; k < NBR_FEA; ++k){
    float w0 = fc_w[(128 + k) * 128 + lane];
    float w1 = fc_w[(128 + k) * 128 + 64 + lane];
    wbp[k] = pack2(w0, w1);
  }
  const float sc0 = stats1[lane],       sc1 = stats1[64 + lane];
  const float tc0 = stats1[128 + lane], tc1 = stats1[192 + lane];
  const int gw = blockIdx.x * 4 + w, nw = gridDim.x * 4;
  const int q = N_ATOMS / nw, rr = N_ATOMS % nw;
  const int a0 = gw * q + (gw < rr ? gw : rr);
  const int a1 = a0 + q + (gw < rr ? 1 : 0);
  float bs = 0.f, bq = 0.f;
  for (int a = a0; a < a1; ++a){
    const int au = __builtin_amdgcn_readfirstlane(a);
    const int base = au * M_NBR;
    const int* jrow = nbr_idx + base;
    unsigned p1v = proj1p[(size_t)au * 64 + lane];
    LOADRW(0) LOADRW(1) LOADRW(2) LOADRW(3) LOADRW(4) LOADRW(5)
    LOADRW(6) LOADRW(7) LOADRW(8) LOADRW(9) LOADRW(10) LOADRW(11)
    const float p10 = unlo(p1v), p11 = unhi(p1v);
    float acc = 0.f;
    GBODYR(0) GBODYR(1) GBODYR(2) GBODYR(3) GBODYR(4) GBODYR(5)
    GBODYR(6) GBODYR(7) GBODYR(8) GBODYR(9) GBODYR(10) GBODYR(11)
    nbr_sumed[(size_t)au * 64 + lane] = acc;
    bs += acc; bq += acc * acc;
  }
  red[w * 128 + lane]      = bs;
  red[w * 128 + 64 + lane] = bq;
  __syncthreads();
  if (tid < 128){
    float v = red[tid] + red[128 + tid] + red[256 + tid] + red[384 + tid];
    part2[blockIdx.x * 128 + tid] = v;
  }
}

// ---- parallel BN2 finish: 64 blocks (r21 proven) ---------------------------
__global__ __launch_bounds__(256) void k_red_fin(
    const float* __restrict__ part2, const float* __restrict__ bn2_g,
    const float* __restrict__ bn2_b, float* __restrict__ stats2)
{
  __shared__ float red[256];
  const int c = blockIdx.x;
  const int t = threadIdx.x;
  float s = 0.f, q = 0.f;
#pragma unroll
  for (int i = t; i < NBLK_MAIN; i += 256){
    s += part2[(size_t)i * 128 + c];
    q += part2[(size_t)i * 128 + 64 + c];
  }
  red[t] = s; __syncthreads();
  for (int o = 128; o > 0; o >>= 1){ if (t < o) red[t] += red[t + o]; __syncthreads(); }
  float sumv = red[0]; __syncthreads();
  red[t] = q; __syncthreads();
  for (int o = 128; o > 0; o >>= 1){ if (t < o) red[t] += red[t + o]; __syncthreads(); }
  if (t == 0){
    const float inv = 1.f / (float)N_ATOMS;
    float mu = sumv * inv;
    float var = red[0] * inv - mu * mu;
    float sc = bn2_g[c] * rsqrtf(var + EPSV);
    stats2[c] = sc;
    stats2[64 + c] = bn2_b[c] - mu * sc;
  }
}

// ---------------- K5: out = softplus(atom_tf + BN2(nbr_sumed)), float4 ------
__global__ __launch_bounds__(256) void k_final(
    const float* __restrict__ atom_tf, const float* __restrict__ ns,
    const float* __restrict__ stats2, float* __restrict__ out)
{
  int i = blockIdx.x * 256 + threadIdx.x;   // one float4 per thread
  if (i >= N_ATOMS * 16) return;            // N*64/4
  int c0 = (i * 4) & 63;
  float4 av = ((const float4*)atom_tf)[i];
  float4 nv = ((const float4*)ns)[i];
  float4 o;
  o.x = softplusf(av.x + nv.x * stats2[c0]     + stats2[64 + c0]);
  o.y = softplusf(av.y + nv.y * stats2[c0 + 1] + stats2[64 + c0 + 1]);
  o.z = softplusf(av.z + nv.z * stats2[c0 + 2] + stats2[64 + c0 + 2]);
  o.w = softplusf(av.w + nv.w * stats2[c0 + 3] + stats2[64 + c0 + 3]);
  ((float4*)out)[i] = o;
}

extern "C" void kernel_launch(void* const* d_in, const int* in_sizes, int n_in,
                              void* d_out, int out_size, void* d_ws, size_t ws_size,
                              hipStream_t stream)
{
  const float* atom_in = (const float*)d_in[0];
  const float* nbr_fea = (const float*)d_in[1];
  const float* adj     = (const float*)d_in[2];
  const float* w1 = (const float*)d_in[3];
  const float* b1 = (const float*)d_in[4];
  const float* w2 = (const float*)d_in[5];
  const float* b2 = (const float*)d_in[6];
  const float* tln1_g = (const float*)d_in[7];
  const float* tln1_b = (const float*)d_in[8];
  const float* tln2_g = (const float*)d_in[9];
  const float* tln2_b = (const float*)d_in[10];
  const float* fc_w = (const float*)d_in[11];
  const float* fc_b = (const float*)d_in[12];
  const float* bn1_g = (const float*)d_in[13];
  const float* bn1_b = (const float*)d_in[14];
  const float* bn2_g = (const float*)d_in[15];
  const float* bn2_b = (const float*)d_in[16];
  const int* nbr_idx = (const int*)d_in[17];
  const int* cidx    = (const int*)d_in[18];
  float* out = (float*)d_out;

  char* ws = (char*)d_ws;
  size_t off = 0;
  float* atom_tf = (float*)(ws + off);    off += (size_t)N_ATOMS * 64 * 4;
  unsigned* proj1p = (unsigned*)(ws + off); off += (size_t)N_ATOMS * 64 * 4;
  unsigned* proj2p = (unsigned*)(ws + off); off += (size_t)N_ATOMS * 64 * 4;
  float* nbr_sumed = (float*)(ws + off);  off += (size_t)N_ATOMS * 64 * 4;
  float* part1 = (float*)(ws + off);      off += (size_t)NBLK_MAIN * 256 * 4;
  float* stats1 = (float*)(ws + off);     off += 256 * 4;
  float* part2 = (float*)(ws + off);      off += (size_t)NBLK_MAIN * 128 * 4;
  float* stats2 = (float*)(ws + off);     off += 128 * 4;
  unsigned* wpk = (unsigned*)(ws + off);  off += 21 * 128 * 4;
  unsigned* gated = (unsigned*)(ws + off);
  const size_t need_gated = off + (size_t)N_ATOMS * M_NBR * 64 * 4;
  const bool use_gated = (ws_size >= need_gated);

  float* ln1 = nbr_sumed;

  k_prep<<<11, 256, 0, stream>>>(fc_w, wpk);
  k_attn<<<B_CRY, 512, 0, stream>>>(atom_in, adj, tln1_g, tln1_b, cidx, ln1);
  k_ff<<<2048, 256, 0, stream>>>(ln1, atom_in, cidx, w1, b1, w2, b2,
      tln2_g, tln2_b, fc_w, fc_b, atom_tf, proj1p, proj2p);
  if (use_gated){
    k_stats<1><<<NBLK_MAIN, 256, 0, stream>>>(nbr_fea, nbr_idx, wpk, proj1p,
        proj2p, part1, gated);
    k_stats_fin<<<128, 256, 0, stream>>>(part1, bn1_g, bn1_b, stats1);
    k_reduce_g<<<NBLK_MAIN, 256, 0, stream>>>(gated, stats1, nbr_sumed, part2);
  } else {
    k_stats<0><<<NBLK_MAIN, 256, 0, stream>>>(nbr_fea, nbr_idx, wpk, proj1p,
        proj2p, part1, gated);
    k_stats_fin<<<128, 256, 0, stream>>>(part1, bn1_g, bn1_b, stats1);
    k_reduce_r<<<NBLK_MAIN, 256, 0, stream>>>(nbr_fea, nbr_idx, fc_w, proj1p,
        proj2p, stats1, nbr_sumed, part2);
  }
  k_red_fin<<<64, 256, 0, stream>>>(part2, bn2_g, bn2_b, stats2);
  k_final<<<(N_ATOMS * 16 + 255) / 256, 256, 0, stream>>>(atom_tf, nbr_sumed, stats2, out);
}